// Round 2
// baseline (2560.115 us; speedup 1.0000x reference)
//
#include <hip/hip_runtime.h>
#include <hip/hip_bf16.h>
#include <cstdint>
#include <cstddef>

// Problem dims
#define BB 4
#define LL 2048
#define EE 7
#define DD 512
#define HH 8
#define DHH 64
#define PP 720
#define NLAYER 2
#define UU 40
#define SCALE 0.125f
#define ROWS (BB*LL)                  // 8192
#define BIGN ((size_t)ROWS*DD)        // 4194304 floats per big buffer
#define NIN 21

typedef unsigned short u16;

__device__ __forceinline__ float bf2f(u16 u){
  union { uint32_t i; float f; } c; c.i = ((uint32_t)u) << 16; return c.f;
}

// ---------------- dtype probe: ln1_g[0] == 1.0 ----------------
// fp32 -> first u32 is 0x3F800000 ; bf16 -> first u32 is 0x3F803F80
__global__ void k_probe(const void* __restrict__ g, int* __restrict__ flag){
  if (threadIdx.x == 0 && blockIdx.x == 0){
    uint32_t bits = *(const uint32_t*)g;
    *flag = (bits == 0x3F800000u) ? 0 : 1;   // 1 = bf16 inputs
  }
}

struct ConvArgs { const void* src[NIN]; int off[NIN]; int n[NIN]; };

// ---------------- convert every input to fp32 staging ----------------
__global__ __launch_bounds__(256) void k_convert(ConvArgs a, float* __restrict__ dst,
    const int* __restrict__ flag){
  int id = blockIdx.y;
  int i = blockIdx.x*256 + threadIdx.x;
  if (i >= a.n[id]) return;
  float v;
  if (*flag) v = bf2f(((const u16*)a.src[id])[i]);
  else       v = ((const float*)a.src[id])[i];
  dst[(size_t)a.off[id] + i] = v;
}

// ---------------- embed: h[r,d] = x[r,:] @ emb_w + emb_b ----------------
__global__ __launch_bounds__(256) void k_embed(const float* __restrict__ x, const float* __restrict__ w,
    const float* __restrict__ b, float* __restrict__ h){
  int i = blockIdx.x*256 + threadIdx.x;
  int d = i & (DD-1); int r = i >> 9;
  const float* xr = x + r*EE;
  float acc = b[d];
  #pragma unroll
  for (int e=0;e<EE;e++) acc = fmaf(xr[e], w[e*DD+d], acc);
  h[i] = acc;
}

// ---------------- GEMM: C[8192,512] = A @ W + bias, opt relu (all fp32) ----
__global__ __launch_bounds__(256) void k_gemm(const float* __restrict__ A, const float* __restrict__ W,
    const float* __restrict__ bias, float* __restrict__ C, int relu){
  int nb = blockIdx.x * 64;
  int mb = blockIdx.y * 64;
  int t = threadIdx.x, tx = t & 15, ty = t >> 4;
  __shared__ float As[16][64];
  __shared__ float Ws[16][64];
  float acc[4][4];
  #pragma unroll
  for (int i=0;i<4;i++)
    #pragma unroll
    for (int j=0;j<4;j++) acc[i][j]=0.f;
  int lm = t >> 2, lk = (t & 3) * 4;     // A: row lm (0..63), k offset lk
  int wk = t >> 4, wn = (t & 15) * 4;    // W: k row wk (0..15), n offset wn
  const float* Ap = A + (size_t)(mb+lm)*DD + lk;
  const float* Wp = W + (size_t)wk*DD + nb + wn;
  for (int k0 = 0; k0 < DD; k0 += 16){
    float4 av = *(const float4*)(Ap + k0);
    float4 wv = *(const float4*)(Wp + (size_t)k0*DD);
    __syncthreads();
    As[lk+0][lm]=av.x; As[lk+1][lm]=av.y; As[lk+2][lm]=av.z; As[lk+3][lm]=av.w;
    Ws[wk][wn+0]=wv.x; Ws[wk][wn+1]=wv.y; Ws[wk][wn+2]=wv.z; Ws[wk][wn+3]=wv.w;
    __syncthreads();
    #pragma unroll
    for (int kk=0; kk<16; ++kk){
      float a[4], w4[4];
      #pragma unroll
      for (int i=0;i<4;i++) a[i]=As[kk][ty+16*i];
      #pragma unroll
      for (int j=0;j<4;j++) w4[j]=Ws[kk][tx+16*j];
      #pragma unroll
      for (int i=0;i<4;i++)
        #pragma unroll
        for (int j=0;j<4;j++) acc[i][j]=fmaf(a[i],w4[j],acc[i][j]);
    }
  }
  #pragma unroll
  for (int j=0;j<4;j++){
    float bv = bias[nb + tx + 16*j];
    #pragma unroll
    for (int i=0;i<4;i++){
      float c = acc[i][j] + bv;
      if (relu) c = fmaxf(c, 0.f);
      C[(size_t)(mb + ty + 16*i)*DD + nb + tx + 16*j] = c;
    }
  }
}

// ---------------- per-(b,h): ksum[d] = sum_l k, vmean[d] = mean_l v ----------------
__global__ __launch_bounds__(256) void k_kvsum(const float* __restrict__ kb, const float* __restrict__ vb,
    float* __restrict__ ksum, float* __restrict__ vmean){
  int bh = blockIdx.x; int b = bh >> 3, hh = bh & 7;
  int t = threadIdx.x, d = t & 63, ch = t >> 6;
  size_t base = (size_t)b*LL*DD + (size_t)hh*DHH + d;
  float ks=0.f, vs=0.f;
  for (int l = ch*512; l < ch*512 + 512; ++l){
    ks += kb[base + (size_t)l*DD];
    vs += vb[base + (size_t)l*DD];
  }
  __shared__ float rk[256], rv[256];
  rk[t]=ks; rv[t]=vs;
  __syncthreads();
  if (t < 64){
    ksum[bh*DHH + d]  = rk[t]+rk[t+64]+rk[t+128]+rk[t+192];
    vmean[bh*DHH + d] = (rv[t]+rv[t+64]+rv[t+128]+rv[t+192]) * (1.0f/LL);
  }
}

// ---------------- M[q] = SCALE*(max_k q.k - (q.ksum)/L), no score materialization ----
__global__ __launch_bounds__(256) void k_sparsity(const float* __restrict__ qb, const float* __restrict__ kb,
    const float* __restrict__ ksum, float* __restrict__ Mout){
  int bh = blockIdx.y; int b = bh >> 3, hh = bh & 7;
  int q0 = blockIdx.x * 64;
  int t = threadIdx.x, tx = t & 15, ty = t >> 4;
  __shared__ float Qs[64][65];   // [d][m]
  __shared__ float Ks[64][65];   // [d][n]
  __shared__ float red[16][64];
  const float* qbase = qb + (size_t)(b*LL + q0)*DD + (size_t)hh*DHH;
  const float* kbase = kb + (size_t)b*LL*DD + (size_t)hh*DHH;
  {
    int m = t >> 2, dg = (t & 3) * 4;
    #pragma unroll
    for (int rep=0; rep<4; ++rep){
      int d = dg + rep*16;
      float4 v = *(const float4*)(qbase + (size_t)m*DD + d);
      Qs[d][m]=v.x; Qs[d+1][m]=v.y; Qs[d+2][m]=v.z; Qs[d+3][m]=v.w;
    }
  }
  float mx[4] = {-3.0e38f, -3.0e38f, -3.0e38f, -3.0e38f};
  for (int kt = 0; kt < LL; kt += 64){
    __syncthreads();
    {
      int n = t >> 2, dg = (t & 3)*4;
      #pragma unroll
      for (int rep=0; rep<4; ++rep){
        int d = dg + rep*16;
        float4 v = *(const float4*)(kbase + (size_t)(kt+n)*DD + d);
        Ks[d][n]=v.x; Ks[d+1][n]=v.y; Ks[d+2][n]=v.z; Ks[d+3][n]=v.w;
      }
    }
    __syncthreads();
    float acc[4][4];
    #pragma unroll
    for (int i=0;i<4;i++)
      #pragma unroll
      for (int j=0;j<4;j++) acc[i][j]=0.f;
    #pragma unroll 16
    for (int d=0; d<64; ++d){
      float a[4], w4[4];
      #pragma unroll
      for (int i=0;i<4;i++) a[i]=Qs[d][ty+16*i];
      #pragma unroll
      for (int j=0;j<4;j++) w4[j]=Ks[d][tx+16*j];
      #pragma unroll
      for (int i=0;i<4;i++)
        #pragma unroll
        for (int j=0;j<4;j++) acc[i][j]=fmaf(a[i],w4[j],acc[i][j]);
    }
    #pragma unroll
    for (int i=0;i<4;i++){
      float m2 = fmaxf(fmaxf(acc[i][0],acc[i][1]), fmaxf(acc[i][2],acc[i][3]));
      mx[i] = fmaxf(mx[i], m2);
    }
  }
  __syncthreads();
  red[tx][ty]=mx[0]; red[tx][ty+16]=mx[1]; red[tx][ty+32]=mx[2]; red[tx][ty+48]=mx[3];
  __syncthreads();
  if (t < 64){
    float best = red[0][t];
    #pragma unroll
    for (int j=1;j<16;j++) best = fmaxf(best, red[j][t]);
    float dot = 0.f;
    #pragma unroll 16
    for (int d=0; d<64; ++d) dot += Qs[d][t] * ksum[bh*DHH + d];
    Mout[bh*LL + q0 + t] = SCALE * (best - dot * (1.0f/LL));
  }
}

// ---------------- top-U selection (stable: ties -> smaller index) ----------------
__global__ __launch_bounds__(256) void k_topk(const float* __restrict__ M, int* __restrict__ sidx){
  int bh = blockIdx.x; int t = threadIdx.x;
  __shared__ float vals[LL];
  __shared__ float rv[256]; __shared__ int ri[256];
  for (int j = t; j < LL; j += 256) vals[j] = M[bh*LL + j];
  __syncthreads();
  for (int it = 0; it < UU; ++it){
    float best = -3.0e38f; int barg = LL;
    for (int j = t; j < LL; j += 256){
      float v = vals[j];
      if (v > best){ best = v; barg = j; }   // increasing j: first hit = smallest idx
    }
    rv[t]=best; ri[t]=barg;
    __syncthreads();
    for (int s=128; s>0; s>>=1){
      if (t < s){
        float v2 = rv[t+s]; int i2 = ri[t+s];
        if (v2 > rv[t] || (v2 == rv[t] && i2 < ri[t])){ rv[t]=v2; ri[t]=i2; }
      }
      __syncthreads();
    }
    if (t == 0){ sidx[bh*UU + it] = ri[0]; vals[ri[0]] = -3.4e38f; }
    __syncthreads();
  }
}

// ---------------- ctx default = vmean broadcast ----------------
__global__ __launch_bounds__(256) void k_fill_ctx(const float* __restrict__ vmean, float* __restrict__ ctx){
  int i = blockIdx.x*256 + threadIdx.x;
  int c = i & (DD-1);
  int b = i >> 20;               // L*D = 2^20
  ctx[i] = vmean[(b << 9) + c];
}

// ---------------- s_top[bh,u,l] = SCALE * q_sel . k_l ----------------
__global__ __launch_bounds__(256) void k_scores(const float* __restrict__ qb, const float* __restrict__ kb,
    const int* __restrict__ sidx, float* __restrict__ st){
  int bh = blockIdx.y; int b = bh >> 3, hh = bh & 7;
  int l0 = blockIdx.x * 64;
  int t = threadIdx.x;
  __shared__ float Ks[64][65];   // [d][l]
  __shared__ float Qs[64][UU];   // [d][u]
  const float* kbase = kb + (size_t)b*LL*DD + (size_t)hh*DHH;
  {
    int n = t >> 2, dg = (t & 3) * 4;
    #pragma unroll
    for (int rep=0; rep<4; ++rep){
      int d = dg + rep*16;
      float4 v = *(const float4*)(kbase + (size_t)(l0+n)*DD + d);
      Ks[d][n]=v.x; Ks[d+1][n]=v.y; Ks[d+2][n]=v.z; Ks[d+3][n]=v.w;
    }
  }
  for (int i = t; i < UU*DHH; i += 256){
    int u = i >> 6, d = i & 63;
    int qrow = sidx[bh*UU + u];
    Qs[d][u] = qb[(size_t)(b*LL + qrow)*DD + (size_t)hh*DHH + d];
  }
  __syncthreads();
  int l = t & 63, uc = t >> 6;
  #pragma unroll
  for (int i = 0; i < 10; ++i){
    int u = uc + 4*i;
    float acc = 0.f;
    #pragma unroll 16
    for (int d=0; d<64; ++d) acc = fmaf(Qs[d][u], Ks[d][l], acc);
    st[(size_t)(bh*UU + u)*LL + l0 + l] = acc * SCALE;
  }
}

// ---------------- softmax(s_top row) then PV, scatter into ctx ----------------
__global__ __launch_bounds__(256) void k_attn_pv(const float* __restrict__ st, const float* __restrict__ vb,
    const int* __restrict__ sidx, float* __restrict__ ctx){
  int gid = blockIdx.x;                 // = bh*UU + u
  int bh = gid / UU;
  int b = bh >> 3, hh = bh & 7;
  int t = threadIdx.x;
  __shared__ float p[LL];
  __shared__ float red[256];
  const float* srow = st + (size_t)gid * LL;
  float lv[8]; float vmax = -3.0e38f;
  #pragma unroll
  for (int j=0;j<8;j++){ lv[j] = srow[t + 256*j]; vmax = fmaxf(vmax, lv[j]); }
  red[t] = vmax; __syncthreads();
  for (int s=128;s>0;s>>=1){ if (t<s) red[t]=fmaxf(red[t], red[t+s]); __syncthreads(); }
  vmax = red[0]; __syncthreads();
  float lsum = 0.f;
  #pragma unroll
  for (int j=0;j<8;j++){ float e = __expf(lv[j]-vmax); p[t+256*j]=e; lsum += e; }
  red[t] = lsum; __syncthreads();
  for (int s=128;s>0;s>>=1){ if (t<s) red[t]+=red[t+s]; __syncthreads(); }
  float inv = 1.0f / red[0];
  __syncthreads();
  int d = t & 63, ch = t >> 6;
  const float* vbase = vb + (size_t)b*LL*DD + (size_t)hh*DHH + d;
  float acc = 0.f;
  for (int l = ch*512; l < ch*512+512; ++l) acc = fmaf(p[l], vbase[(size_t)l*DD], acc);
  red[t] = acc; __syncthreads();
  if (t < 64){
    float o = (red[t]+red[t+64]+red[t+128]+red[t+192]) * inv;
    int qrow = sidx[gid];
    ctx[(size_t)(b*LL + qrow)*DD + (size_t)hh*DHH + t] = o;
  }
}

// ---------------- out = LayerNorm(a + r) * g + b (all fp32) ----------------
__global__ __launch_bounds__(256) void k_addln(const float* __restrict__ a, const float* __restrict__ r,
    const float* __restrict__ g, const float* __restrict__ bvec, float* __restrict__ out){
  int row = blockIdx.x; int t = threadIdx.x;
  size_t base = (size_t)row * DD;
  float v0 = a[base+t] + r[base+t];
  float v1 = a[base+t+256] + r[base+t+256];
  __shared__ float red[256];
  red[t] = v0+v1; __syncthreads();
  for (int s=128;s>0;s>>=1){ if (t<s) red[t]+=red[t+s]; __syncthreads(); }
  float mean = red[0] * (1.0f/DD);
  __syncthreads();
  float d0 = v0-mean, d1 = v1-mean;
  red[t] = d0*d0 + d1*d1; __syncthreads();
  for (int s=128;s>0;s>>=1){ if (t<s) red[t]+=red[t+s]; __syncthreads(); }
  float rs = rsqrtf(red[0]*(1.0f/DD) + 1e-5f);
  out[base+t]     = d0*rs*g[t]     + bvec[t];
  out[base+t+256] = d1*rs*g[t+256] + bvec[t+256];
}

// ---------------- final projection: out[b,p,:] = h[row,:] @ proj_w + proj_b ----------------
__global__ __launch_bounds__(64) void k_proj(const float* __restrict__ h, const float* __restrict__ pw,
    const float* __restrict__ pb, void* __restrict__ out, const int* __restrict__ flag){
  int rp = blockIdx.x; int b = rp / PP, pp = rp % PP;
  int t = threadIdx.x;
  const float* hr = h + (size_t)(b*LL + (LL-PP) + pp) * DD;
  float acc[EE];
  #pragma unroll
  for (int e=0;e<EE;e++) acc[e]=0.f;
  for (int d = t; d < DD; d += 64){
    float hv = hr[d];
    #pragma unroll
    for (int e=0;e<EE;e++) acc[e] = fmaf(hv, pw[d*EE+e], acc[e]);
  }
  int isbf = *flag;
  #pragma unroll
  for (int e=0;e<EE;e++){
    float rr = acc[e];
    for (int off=32; off>0; off>>=1) rr += __shfl_down(rr, off);
    if (t == 0){
      float val = rr + pb[e];
      if (isbf) ((__hip_bfloat16*)out)[(size_t)rp*EE + e] = __float2bfloat16(val);
      else      ((float*)out)[(size_t)rp*EE + e] = val;
    }
  }
}

extern "C" void kernel_launch(void* const* d_in, const int* in_sizes, int n_in,
                              void* d_out, int out_size, void* d_ws, size_t ws_size,
                              hipStream_t stream){
  float* ws   = (float*)d_ws;
  float* h    = ws;
  float* qb   = ws + 1*BIGN;
  float* kb   = ws + 2*BIGN;
  float* vb   = ws + 3*BIGN;
  float* ctx  = ws + 4*BIGN;
  float* Mv   = ws + 5*BIGN;                        // B*H*L = 65536
  float* ksum = Mv + (size_t)BB*HH*LL;              // 2048
  float* vmean= ksum + BB*HH*DHH;                   // 2048
  float* st   = vmean + BB*HH*DHH;                  // B*H*U*L = 2621440
  int*   sidx = (int*)(st + (size_t)BB*HH*UU*LL);   // 1280 ints
  int*   flag = sidx + 1280;
  float* conv = (float*)(flag + 4);                 // fp32 staging for all inputs
  float* attn = qb;   // alias: free after attention
  float* f1   = kb;   // alias: free after attention
  float* f2   = vb;   // alias: free after attention

  // fp32 staging offsets
  ConvArgs ca;
  size_t tot = 0;
  int maxn = 0;
  for (int i = 0; i < NIN; ++i){
    ca.src[i] = d_in[i];
    ca.off[i] = (int)tot;
    ca.n[i]   = in_sizes[i];
    tot += in_sizes[i];
    if (in_sizes[i] > maxn) maxn = in_sizes[i];
  }
  const float* x     = conv + ca.off[0];
  const float* emb_w = conv + ca.off[1];
  const float* emb_b = conv + ca.off[2];
  const float* Wq = conv + ca.off[3];  const float* bq = conv + ca.off[4];
  const float* Wk = conv + ca.off[5];  const float* bk = conv + ca.off[6];
  const float* Wv = conv + ca.off[7];  const float* bv = conv + ca.off[8];
  const float* Wo = conv + ca.off[9];  const float* bo = conv + ca.off[10];
  const float* W1 = conv + ca.off[11]; const float* b1 = conv + ca.off[12];
  const float* W2 = conv + ca.off[13]; const float* b2 = conv + ca.off[14];
  const float* ln1g = conv + ca.off[15]; const float* ln1b = conv + ca.off[16];
  const float* ln2g = conv + ca.off[17]; const float* ln2b = conv + ca.off[18];
  const float* pw = conv + ca.off[19]; const float* pb = conv + ca.off[20];

  k_probe<<<1, 64, 0, stream>>>(d_in[15], flag);
  k_convert<<<dim3((maxn + 255)/256, NIN), 256, 0, stream>>>(ca, conv, flag);

  dim3 gg(DD/64, ROWS/64);   // (8,128)

  k_embed<<<ROWS*DD/256, 256, 0, stream>>>(x, emb_w, emb_b, h);
  for (int l = 0; l < NLAYER; ++l){
    const float* Wq_l = Wq + (size_t)l*DD*DD; const float* bq_l = bq + l*DD;
    const float* Wk_l = Wk + (size_t)l*DD*DD; const float* bk_l = bk + l*DD;
    const float* Wv_l = Wv + (size_t)l*DD*DD; const float* bv_l = bv + l*DD;
    const float* Wo_l = Wo + (size_t)l*DD*DD; const float* bo_l = bo + l*DD;
    const float* W1_l = W1 + (size_t)l*DD*DD; const float* b1_l = b1 + l*DD;
    const float* W2_l = W2 + (size_t)l*DD*DD; const float* b2_l = b2 + l*DD;

    k_gemm<<<gg, 256, 0, stream>>>(h, Wq_l, bq_l, qb, 0);
    k_gemm<<<gg, 256, 0, stream>>>(h, Wk_l, bk_l, kb, 0);
    k_gemm<<<gg, 256, 0, stream>>>(h, Wv_l, bv_l, vb, 0);
    k_kvsum<<<BB*HH, 256, 0, stream>>>(kb, vb, ksum, vmean);
    k_sparsity<<<dim3(LL/64, BB*HH), 256, 0, stream>>>(qb, kb, ksum, Mv);
    k_topk<<<BB*HH, 256, 0, stream>>>(Mv, sidx);
    k_fill_ctx<<<ROWS*DD/256, 256, 0, stream>>>(vmean, ctx);
    k_scores<<<dim3(LL/64, BB*HH), 256, 0, stream>>>(qb, kb, sidx, st);
    k_attn_pv<<<BB*HH*UU, 256, 0, stream>>>(st, vb, sidx, ctx);
    k_gemm<<<gg, 256, 0, stream>>>(ctx, Wo_l, bo_l, attn, 0);
    k_addln<<<ROWS, 256, 0, stream>>>(h, attn, ln1g + l*DD, ln1b + l*DD, h);
    k_gemm<<<gg, 256, 0, stream>>>(h, W1_l, b1_l, f1, 1);
    k_gemm<<<gg, 256, 0, stream>>>(f1, W2_l, b2_l, f2, 0);
    k_addln<<<ROWS, 256, 0, stream>>>(h, f2, ln2g + l*DD, ln2b + l*DD, h);
  }
  k_proj<<<BB*PP, 64, 0, stream>>>(h, pw, pb, d_out, flag);
}

// Round 3
// 1209.123 us; speedup vs baseline: 2.1173x; 2.1173x over previous
//
#include <hip/hip_runtime.h>
#include <hip/hip_bf16.h>
#include <cstdint>
#include <cstddef>

// Problem dims
#define BB 4
#define LL 2048
#define EE 7
#define DD 512
#define HH 8
#define DHH 64
#define PP 720
#define NLAYER 2
#define UU 40
#define SCALE 0.125f
#define ROWS (BB*LL)                  // 8192
#define BIGN ((size_t)ROWS*DD)        // 4194304 elements per big buffer
#define NIN 21

typedef unsigned short u16;
typedef __bf16 bf16x8 __attribute__((ext_vector_type(8)));
typedef float  f32x4  __attribute__((ext_vector_type(4)));

__device__ __forceinline__ float bf2f(u16 u){
  union { uint32_t i; float f; } c; c.i = ((uint32_t)u) << 16; return c.f;
}
__device__ __forceinline__ u16 f2b(float f){
  __hip_bfloat16 h = __float2bfloat16(f);
  return *(u16*)&h;
}
__device__ __forceinline__ void gld_lds16(const u16* g, u16* l){
  __builtin_amdgcn_global_load_lds(
      (const __attribute__((address_space(1))) uint32_t*)g,
      (__attribute__((address_space(3))) uint32_t*)l, 16, 0, 0);
}

// ---------------- dtype probe: ln1_g[0] == 1.0 ----------------
__global__ void k_probe(const void* __restrict__ g, int* __restrict__ flag){
  if (threadIdx.x == 0 && blockIdx.x == 0){
    uint32_t bits = *(const uint32_t*)g;
    *flag = (bits == 0x3F800000u) ? 0 : 1;   // 1 = bf16 inputs
  }
}

#define NSMALL 15
struct ConvArgs { const void* src[NSMALL]; int off[NSMALL]; int n[NSMALL]; };

// ---------------- convert small inputs to fp32 staging ----------------
__global__ __launch_bounds__(256) void k_convert(ConvArgs a, float* __restrict__ dst,
    const int* __restrict__ flag){
  int id = blockIdx.y;
  int i = blockIdx.x*256 + threadIdx.x;
  if (i >= a.n[id]) return;
  float v;
  if (*flag) v = bf2f(((const u16*)a.src[id])[i]);
  else       v = ((const float*)a.src[id])[i];
  dst[(size_t)a.off[id] + i] = v;
}

// ---------------- weights -> bf16 W^T staging: dst[mz][n][k] = W[mz.layer][k][n] ----
struct WPtrs { const void* p[6]; };
__global__ __launch_bounds__(256) void k_wt(WPtrs wp, u16* __restrict__ dst,
    const int* __restrict__ flag){
  int mz = blockIdx.z; int mat = mz / NLAYER, lay = mz % NLAYER;
  int n0 = blockIdx.x*64, k0 = blockIdx.y*64;
  int t = threadIdx.x; int r = t >> 6, c = t & 63;
  __shared__ u16 tile[64][65];   // tile[k_local][n_local]
  int isbf = *flag;
  const void* src = wp.p[mat];
  for (int rr = r; rr < 64; rr += 4){
    size_t idx = ((size_t)lay*DD + (k0+rr))*DD + n0 + c;
    u16 v;
    if (isbf) v = ((const u16*)src)[idx];
    else      v = f2b(((const float*)src)[idx]);
    tile[rr][c] = v;
  }
  __syncthreads();
  u16* drow = dst + ((size_t)mz*DD + n0)*DD + k0;
  for (int rr = r; rr < 64; rr += 4)
    drow[(size_t)rr*DD + c] = tile[c][rr];
}

// ---------------- embed: h[r,d] = x[r,:] @ emb_w + emb_b (fp32 + bf16 out) ----------
__global__ __launch_bounds__(256) void k_embed(const float* __restrict__ x, const float* __restrict__ w,
    const float* __restrict__ b, float* __restrict__ h, u16* __restrict__ hB){
  int i = blockIdx.x*256 + threadIdx.x;
  int d = i & (DD-1); int r = i >> 9;
  const float* xr = x + r*EE;
  float acc = b[d];
  #pragma unroll
  for (int e=0;e<EE;e++) acc = fmaf(xr[e], w[e*DD+d], acc);
  h[i] = acc;
  hB[i] = f2b(acc);
}

// ---------------- MFMA GEMM: C[8192,512] = A(bf16) @ Bt(bf16)^T + bias ----------------
// A row-major [M][512], Bt row-major [N][512] (= W^T). 128x128 tile, BK=64.
__global__ __launch_bounds__(256) void k_gemm_mfma(const u16* __restrict__ A, const u16* __restrict__ Bt,
    const float* __restrict__ bias, float* __restrict__ Cf, u16* __restrict__ Cb, int relu){
  __shared__ u16 As[128*64];
  __shared__ u16 Bs[128*64];
  int t = threadIdx.x, wave = t >> 6, lane = t & 63;
  int mb = blockIdx.y * 128, nb = blockIdx.x * 128;
  int wm = (wave & 1) * 64, wn = (wave >> 1) * 64;
  f32x4 acc[4][4];
  #pragma unroll
  for (int i=0;i<4;i++)
    #pragma unroll
    for (int j=0;j<4;j++) acc[i][j] = (f32x4){0.f,0.f,0.f,0.f};

  int srow = wave*8 + (lane>>3);          // staging row within 32-row chunk
  int scol = (lane&7)*8;                  // staging col (elements)
  const u16* Ag = A + (size_t)(mb + srow)*DD + scol;
  const u16* Bg = Bt + (size_t)(nb + srow)*DD + scol;

  for (int k0 = 0; k0 < DD; k0 += 64){
    __syncthreads();
    #pragma unroll
    for (int i=0;i<4;i++){
      gld_lds16(Ag + (size_t)i*32*DD + k0, As + (i*32 + wave*8)*64);
      gld_lds16(Bg + (size_t)i*32*DD + k0, Bs + (i*32 + wave*8)*64);
    }
    __syncthreads();
    #pragma unroll
    for (int ch=0; ch<2; ++ch){
      bf16x8 af[4], bf[4];
      int kof = ch*32 + (lane>>4)*8;
      #pragma unroll
      for (int i=0;i<4;i++) af[i] = *(const bf16x8*)(As + (wm + i*16 + (lane&15))*64 + kof);
      #pragma unroll
      for (int j=0;j<4;j++) bf[j] = *(const bf16x8*)(Bs + (wn + j*16 + (lane&15))*64 + kof);
      #pragma unroll
      for (int i=0;i<4;i++)
        #pragma unroll
        for (int j=0;j<4;j++)
          acc[i][j] = __builtin_amdgcn_mfma_f32_16x16x32_bf16(af[i], bf[j], acc[i][j], 0, 0, 0);
    }
  }
  // epilogue: C/D layout col=lane&15, row=(lane>>4)*4+reg
  #pragma unroll
  for (int i=0;i<4;i++){
    int rbase = mb + wm + i*16 + (lane>>4)*4;
    #pragma unroll
    for (int j=0;j<4;j++){
      int col = nb + wn + j*16 + (lane&15);
      float bv = bias[col];
      #pragma unroll
      for (int r=0;r<4;r++){
        float cv = acc[i][j][r] + bv;
        if (relu) cv = fmaxf(cv, 0.f);
        size_t off = (size_t)(rbase + r)*DD + col;
        if (Cf) Cf[off] = cv;
        if (Cb) Cb[off] = f2b(cv);
      }
    }
  }
}

// ---------------- per-(b,h): ksum[d] = sum_l k, vmean[d] = mean_l v ----------------
__global__ __launch_bounds__(256) void k_kvsum(const float* __restrict__ kb, const float* __restrict__ vb,
    float* __restrict__ ksum, float* __restrict__ vmean){
  int bh = blockIdx.x; int b = bh >> 3, hh = bh & 7;
  int t = threadIdx.x, d = t & 63, ch = t >> 6;
  size_t base = (size_t)b*LL*DD + (size_t)hh*DHH + d;
  float ks=0.f, vs=0.f;
  for (int l = ch*512; l < ch*512 + 512; ++l){
    ks += kb[base + (size_t)l*DD];
    vs += vb[base + (size_t)l*DD];
  }
  __shared__ float rk[256], rv[256];
  rk[t]=ks; rv[t]=vs;
  __syncthreads();
  if (t < 64){
    ksum[bh*DHH + d]  = rk[t]+rk[t+64]+rk[t+128]+rk[t+192];
    vmean[bh*DHH + d] = (rv[t]+rv[t+64]+rv[t+128]+rv[t+192]) * (1.0f/LL);
  }
}

// ---------------- MFMA sparsity: M[q] = SCALE*(max_k q.k - (q.ksum)/L) ----------------
__global__ __launch_bounds__(256) void k_sparsity_mfma(const u16* __restrict__ qB, const u16* __restrict__ kB,
    const float* __restrict__ qf, const float* __restrict__ ksum, float* __restrict__ Mout){
  int bh = blockIdx.y; int b = bh >> 3, hh = bh & 7;
  int q0 = blockIdx.x * 64;
  int t = threadIdx.x, wave = t >> 6, lane = t & 63;
  const u16* qbase = qB + ((size_t)(b*LL + q0))*DD + hh*DHH;
  const u16* kbase = kB + ((size_t)b*LL)*DD + hh*DHH;
  bf16x8 qa[4][2];
  #pragma unroll
  for (int i=0;i<4;i++)
    #pragma unroll
    for (int c=0;c<2;c++)
      qa[i][c] = *(const bf16x8*)(qbase + (size_t)(i*16 + (lane&15))*DD + c*32 + (lane>>4)*8);
  float rmax[4][4];
  #pragma unroll
  for (int i=0;i<4;i++)
    #pragma unroll
    for (int r=0;r<4;r++) rmax[i][r] = -3.0e38f;
  for (int kt = wave*16; kt < LL; kt += 64){
    bf16x8 kb0 = *(const bf16x8*)(kbase + (size_t)(kt + (lane&15))*DD + (lane>>4)*8);
    bf16x8 kb1 = *(const bf16x8*)(kbase + (size_t)(kt + (lane&15))*DD + 32 + (lane>>4)*8);
    #pragma unroll
    for (int i=0;i<4;i++){
      f32x4 a = (f32x4){0.f,0.f,0.f,0.f};
      a = __builtin_amdgcn_mfma_f32_16x16x32_bf16(qa[i][0], kb0, a, 0, 0, 0);
      a = __builtin_amdgcn_mfma_f32_16x16x32_bf16(qa[i][1], kb1, a, 0, 0, 0);
      #pragma unroll
      for (int r=0;r<4;r++) rmax[i][r] = fmaxf(rmax[i][r], a[r]);
    }
  }
  // reduce across the 16 key-columns (lane bits 0..3)
  #pragma unroll
  for (int i=0;i<4;i++)
    #pragma unroll
    for (int r=0;r<4;r++){
      float v = rmax[i][r];
      v = fmaxf(v, __shfl_xor(v, 1));
      v = fmaxf(v, __shfl_xor(v, 2));
      v = fmaxf(v, __shfl_xor(v, 4));
      v = fmaxf(v, __shfl_xor(v, 8));
      rmax[i][r] = v;
    }
  __shared__ float smax[4][64];
  if ((lane & 15) == 0){
    #pragma unroll
    for (int i=0;i<4;i++)
      #pragma unroll
      for (int r=0;r<4;r++)
        smax[wave][i*16 + (lane>>4)*4 + r] = rmax[i][r];
  }
  __syncthreads();
  if (t < 64){
    float mx = fmaxf(fmaxf(smax[0][t], smax[1][t]), fmaxf(smax[2][t], smax[3][t]));
    const float* qrow = qf + (size_t)(b*LL + q0 + t)*DD + hh*DHH;
    float dot = 0.f;
    #pragma unroll 16
    for (int d=0; d<DHH; ++d) dot += qrow[d] * ksum[bh*DHH + d];
    Mout[bh*LL + q0 + t] = SCALE * (mx - dot * (1.0f/LL));
  }
}

// ---------------- top-U selection (stable: ties -> smaller index) ----------------
__global__ __launch_bounds__(256) void k_topk(const float* __restrict__ M, int* __restrict__ sidx){
  int bh = blockIdx.x; int t = threadIdx.x;
  __shared__ float vals[LL];
  __shared__ float rv[256]; __shared__ int ri[256];
  for (int j = t; j < LL; j += 256) vals[j] = M[bh*LL + j];
  __syncthreads();
  for (int it = 0; it < UU; ++it){
    float best = -3.0e38f; int barg = LL;
    for (int j = t; j < LL; j += 256){
      float v = vals[j];
      if (v > best){ best = v; barg = j; }
    }
    rv[t]=best; ri[t]=barg;
    __syncthreads();
    for (int s=128; s>0; s>>=1){
      if (t < s){
        float v2 = rv[t+s]; int i2 = ri[t+s];
        if (v2 > rv[t] || (v2 == rv[t] && i2 < ri[t])){ rv[t]=v2; ri[t]=i2; }
      }
      __syncthreads();
    }
    if (t == 0){ sidx[bh*UU + it] = ri[0]; vals[ri[0]] = -3.4e38f; }
    __syncthreads();
  }
}

// ---------------- ctx default = vmean broadcast (bf16) ----------------
__global__ __launch_bounds__(256) void k_fill_ctx(const float* __restrict__ vmean, u16* __restrict__ ctxB){
  int i = blockIdx.x*256 + threadIdx.x;
  int c = i & (DD-1);
  int b = i >> 20;               // L*D = 2^20
  ctxB[i] = f2b(vmean[(b << 9) + c]);
}

// ---------------- s_top[bh,u,l] = SCALE * q_sel . k_l ----------------
__global__ __launch_bounds__(256) void k_scores(const float* __restrict__ qb, const float* __restrict__ kb,
    const int* __restrict__ sidx, float* __restrict__ st){
  int bh = blockIdx.y; int b = bh >> 3, hh = bh & 7;
  int l0 = blockIdx.x * 64;
  int t = threadIdx.x;
  __shared__ float Ks[64][65];   // [d][l]
  __shared__ float Qs[64][UU];   // [d][u]
  const float* kbase = kb + (size_t)b*LL*DD + (size_t)hh*DHH;
  {
    int n = t >> 2, dg = (t & 3) * 4;
    #pragma unroll
    for (int rep=0; rep<4; ++rep){
      int d = dg + rep*16;
      float4 v = *(const float4*)(kbase + (size_t)(l0+n)*DD + d);
      Ks[d][n]=v.x; Ks[d+1][n]=v.y; Ks[d+2][n]=v.z; Ks[d+3][n]=v.w;
    }
  }
  for (int i = t; i < UU*DHH; i += 256){
    int u = i >> 6, d = i & 63;
    int qrow = sidx[bh*UU + u];
    Qs[d][u] = qb[(size_t)(b*LL + qrow)*DD + (size_t)hh*DHH + d];
  }
  __syncthreads();
  int l = t & 63, uc = t >> 6;
  #pragma unroll
  for (int i = 0; i < 10; ++i){
    int u = uc + 4*i;
    float acc = 0.f;
    #pragma unroll 16
    for (int d=0; d<64; ++d) acc = fmaf(Qs[d][u], Ks[d][l], acc);
    st[(size_t)(bh*UU + u)*LL + l0 + l] = acc * SCALE;
  }
}

// ---------------- softmax(s_top row) then PV, scatter into ctxB ----------------
__global__ __launch_bounds__(256) void k_attn_pv(const float* __restrict__ st, const float* __restrict__ vb,
    const int* __restrict__ sidx, u16* __restrict__ ctxB){
  int gid = blockIdx.x;                 // = bh*UU + u
  int bh = gid / UU;
  int b = bh >> 3, hh = bh & 7;
  int t = threadIdx.x;
  __shared__ float p[LL];
  __shared__ float red[256];
  const float* srow = st + (size_t)gid * LL;
  float lv[8]; float vmax = -3.0e38f;
  #pragma unroll
  for (int j=0;j<8;j++){ lv[j] = srow[t + 256*j]; vmax = fmaxf(vmax, lv[j]); }
  red[t] = vmax; __syncthreads();
  for (int s=128;s>0;s>>=1){ if (t<s) red[t]=fmaxf(red[t], red[t+s]); __syncthreads(); }
  vmax = red[0]; __syncthreads();
  float lsum = 0.f;
  #pragma unroll
  for (int j=0;j<8;j++){ float e = __expf(lv[j]-vmax); p[t+256*j]=e; lsum += e; }
  red[t] = lsum; __syncthreads();
  for (int s=128;s>0;s>>=1){ if (t<s) red[t]+=red[t+s]; __syncthreads(); }
  float inv = 1.0f / red[0];
  __syncthreads();
  int d = t & 63, ch = t >> 6;
  const float* vbase = vb + (size_t)b*LL*DD + (size_t)hh*DHH + d;
  float acc = 0.f;
  for (int l = ch*512; l < ch*512+512; ++l) acc = fmaf(p[l], vbase[(size_t)l*DD], acc);
  red[t] = acc; __syncthreads();
  if (t < 64){
    float o = (red[t]+red[t+64]+red[t+128]+red[t+192]) * inv;
    int qrow = sidx[gid];
    ctxB[(size_t)(b*LL + qrow)*DD + (size_t)hh*DHH + t] = f2b(o);
  }
}

// ---------------- out = LayerNorm(a + r) * g + b (fp32 out + bf16 out) ----------------
__global__ __launch_bounds__(256) void k_addln(const float* __restrict__ a, const float* __restrict__ r,
    const float* __restrict__ g, const float* __restrict__ bvec, float* __restrict__ out,
    u16* __restrict__ outB){
  int row = blockIdx.x; int t = threadIdx.x;
  size_t base = (size_t)row * DD;
  float v0 = a[base+t] + r[base+t];
  float v1 = a[base+t+256] + r[base+t+256];
  __shared__ float red[256];
  red[t] = v0+v1; __syncthreads();
  for (int s=128;s>0;s>>=1){ if (t<s) red[t]+=red[t+s]; __syncthreads(); }
  float mean = red[0] * (1.0f/DD);
  __syncthreads();
  float d0 = v0-mean, d1 = v1-mean;
  red[t] = d0*d0 + d1*d1; __syncthreads();
  for (int s=128;s>0;s>>=1){ if (t<s) red[t]+=red[t+s]; __syncthreads(); }
  float rs = rsqrtf(red[0]*(1.0f/DD) + 1e-5f);
  float o0 = d0*rs*g[t]     + bvec[t];
  float o1 = d1*rs*g[t+256] + bvec[t+256];
  out[base+t] = o0;     out[base+t+256] = o1;
  outB[base+t] = f2b(o0); outB[base+t+256] = f2b(o1);
}

// ---------------- final projection ----------------
__global__ __launch_bounds__(64) void k_proj(const float* __restrict__ h, const float* __restrict__ pw,
    const float* __restrict__ pb, void* __restrict__ out, const int* __restrict__ flag){
  int rp = blockIdx.x; int b = rp / PP, pp = rp % PP;
  int t = threadIdx.x;
  const float* hr = h + (size_t)(b*LL + (LL-PP) + pp) * DD;
  float acc[EE];
  #pragma unroll
  for (int e=0;e<EE;e++) acc[e]=0.f;
  for (int d = t; d < DD; d += 64){
    float hv = hr[d];
    #pragma unroll
    for (int e=0;e<EE;e++) acc[e] = fmaf(hv, pw[d*EE+e], acc[e]);
  }
  int isbf = *flag;
  #pragma unroll
  for (int e=0;e<EE;e++){
    float rr = acc[e];
    for (int off=32; off>0; off>>=1) rr += __shfl_down(rr, off);
    if (t == 0){
      float val = rr + pb[e];
      if (isbf) ((__hip_bfloat16*)out)[(size_t)rp*EE + e] = __float2bfloat16(val);
      else      ((float*)out)[(size_t)rp*EE + e] = val;
    }
  }
}

extern "C" void kernel_launch(void* const* d_in, const int* in_sizes, int n_in,
                              void* d_out, int out_size, void* d_ws, size_t ws_size,
                              hipStream_t stream){
  float* ws    = (float*)d_ws;
  float* h     = ws;
  float* qf    = ws + 1*BIGN;
  float* kf    = ws + 2*BIGN;
  float* vf    = ws + 3*BIGN;
  float* Mv    = ws + 4*BIGN;                        // B*H*L = 65536
  float* ksum  = Mv + (size_t)BB*HH*LL;              // 2048
  float* vmean = ksum + BB*HH*DHH;                   // 2048
  float* st    = vmean + BB*HH*DHH;                  // B*H*U*L = 2,621,440
  int*   sidx  = (int*)(st + (size_t)BB*HH*UU*LL);   // 1280 ints
  int*   flag  = sidx + 1280;
  u16*   hB    = (u16*)(flag + 4);
  u16*   qB    = hB + BIGN;
  u16*   kB    = qB + BIGN;
  u16*   ctxB  = kB + BIGN;
  u16*   f1B   = ctxB + BIGN;
  u16*   wT    = f1B + BIGN;                         // [6*NL][512][512] bf16
  float* conv  = (float*)(wT + (size_t)6*NLAYER*DD*DD);
  float* attnF = qf;   // alias: qf free after scores
  float* f2F   = kf;   // alias: kf free after scores/kvsum/sparsity

  // small-tensor fp32 staging (weights go to wT instead)
  static const int small_ids[NSMALL] = {0,1,2,4,6,8,10,12,14,15,16,17,18,19,20};
  ConvArgs ca;
  int off_all[NIN];
  int tot = 0, maxn = 0;
  for (int i = 0; i < NIN; ++i) off_all[i] = -1;
  for (int s = 0; s < NSMALL; ++s){
    int i = small_ids[s];
    ca.src[s] = d_in[i];
    ca.off[s] = tot;
    ca.n[s]   = in_sizes[i];
    off_all[i] = tot;
    tot += in_sizes[i];
    if (in_sizes[i] > maxn) maxn = in_sizes[i];
  }
  const float* x     = conv + off_all[0];
  const float* emb_w = conv + off_all[1];
  const float* emb_b = conv + off_all[2];
  const float* bq = conv + off_all[4];
  const float* bk = conv + off_all[6];
  const float* bv = conv + off_all[8];
  const float* bo = conv + off_all[10];
  const float* b1 = conv + off_all[12];
  const float* b2 = conv + off_all[14];
  const float* ln1g = conv + off_all[15]; const float* ln1b = conv + off_all[16];
  const float* ln2g = conv + off_all[17]; const float* ln2b = conv + off_all[18];
  const float* pw = conv + off_all[19]; const float* pb = conv + off_all[20];

  WPtrs wp;
  wp.p[0]=d_in[3]; wp.p[1]=d_in[5]; wp.p[2]=d_in[7];
  wp.p[3]=d_in[9]; wp.p[4]=d_in[11]; wp.p[5]=d_in[13];

  k_probe<<<1, 64, 0, stream>>>(d_in[15], flag);
  k_convert<<<dim3((maxn + 255)/256, NSMALL), 256, 0, stream>>>(ca, conv, flag);
  k_wt<<<dim3(8, 8, 6*NLAYER), 256, 0, stream>>>(wp, wT, flag);

  dim3 gg(DD/128, ROWS/128);   // (4,64) = 256 blocks

  k_embed<<<ROWS*DD/256, 256, 0, stream>>>(x, emb_w, emb_b, h, hB);
  for (int l = 0; l < NLAYER; ++l){
    const u16* WqT = wT + (size_t)(0*NLAYER + l)*DD*DD;
    const u16* WkT = wT + (size_t)(1*NLAYER + l)*DD*DD;
    const u16* WvT = wT + (size_t)(2*NLAYER + l)*DD*DD;
    const u16* WoT = wT + (size_t)(3*NLAYER + l)*DD*DD;
    const u16* W1T = wT + (size_t)(4*NLAYER + l)*DD*DD;
    const u16* W2T = wT + (size_t)(5*NLAYER + l)*DD*DD;

    k_gemm_mfma<<<gg, 256, 0, stream>>>(hB, WqT, bq + l*DD, qf, qB, 0);
    k_gemm_mfma<<<gg, 256, 0, stream>>>(hB, WkT, bk + l*DD, kf, kB, 0);
    k_gemm_mfma<<<gg, 256, 0, stream>>>(hB, WvT, bv + l*DD, vf, nullptr, 0);
    k_kvsum<<<BB*HH, 256, 0, stream>>>(kf, vf, ksum, vmean);
    k_sparsity_mfma<<<dim3(LL/64, BB*HH), 256, 0, stream>>>(qB, kB, qf, ksum, Mv);
    k_topk<<<BB*HH, 256, 0, stream>>>(Mv, sidx);
    k_fill_ctx<<<ROWS*DD/256, 256, 0, stream>>>(vmean, ctxB);
    k_scores<<<dim3(LL/64, BB*HH), 256, 0, stream>>>(qf, kf, sidx, st);
    k_attn_pv<<<BB*HH*UU, 256, 0, stream>>>(st, vf, sidx, ctxB);
    k_gemm_mfma<<<gg, 256, 0, stream>>>(ctxB, WoT, bo + l*DD, attnF, nullptr, 0);
    k_addln<<<ROWS, 256, 0, stream>>>(h, attnF, ln1g + l*DD, ln1b + l*DD, h, hB);
    k_gemm_mfma<<<gg, 256, 0, stream>>>(hB, W1T, b1 + l*DD, nullptr, f1B, 1);
    k_gemm_mfma<<<gg, 256, 0, stream>>>(f1B, W2T, b2 + l*DD, f2F, nullptr, 0);
    k_addln<<<ROWS, 256, 0, stream>>>(h, f2F, ln2g + l*DD, ln2b + l*DD, h, hB);
  }
  k_proj<<<BB*PP, 64, 0, stream>>>(h, pw, pb, d_out, flag);
}

// Round 4
// 588.270 us; speedup vs baseline: 4.3519x; 2.0554x over previous
//
#include <hip/hip_runtime.h>
#include <hip/hip_bf16.h>
#include <cstdint>
#include <cstddef>

// Problem dims
#define BB 4
#define LL 2048
#define EE 7
#define DD 512
#define HH 8
#define DHH 64
#define PP 720
#define NLAYER 2
#define UU 40
#define SCALE 0.125f
#define ROWS (BB*LL)                  // 8192
#define BIGN ((size_t)ROWS*DD)        // 4194304 elements per big buffer
#define NIN 21
#define FCH 256                       // flash keys per chunk
#define NCH (LL/FCH)                  // 8
#define PSTR 264                      // Ps row stride (u16), 528B: 16B-aligned rows
#define VSTR 136                      // VsT row stride (u16), 272B: 16B-aligned rows

typedef unsigned short u16;
typedef __bf16 bf16x8 __attribute__((ext_vector_type(8)));
typedef float  f32x4  __attribute__((ext_vector_type(4)));

__device__ __forceinline__ float bf2f(u16 u){
  union { uint32_t i; float f; } c; c.i = ((uint32_t)u) << 16; return c.f;
}
__device__ __forceinline__ u16 f2b(float f){
  __hip_bfloat16 h = __float2bfloat16(f);
  return *(u16*)&h;
}
__device__ __forceinline__ void gld_lds16(const u16* g, u16* l){
  __builtin_amdgcn_global_load_lds(
      (const __attribute__((address_space(1))) uint32_t*)g,
      (__attribute__((address_space(3))) uint32_t*)l, 16, 0, 0);
}

// ---------------- dtype probe: ln1_g[0] == 1.0 ----------------
__global__ void k_probe(const void* __restrict__ g, int* __restrict__ flag){
  if (threadIdx.x == 0 && blockIdx.x == 0){
    uint32_t bits = *(const uint32_t*)g;
    *flag = (bits == 0x3F800000u) ? 0 : 1;   // 1 = bf16 inputs
  }
}

#define NSMALL 15
struct ConvArgs { const void* src[NSMALL]; int off[NSMALL]; int n[NSMALL]; };

// ---------------- convert small inputs to fp32 staging ----------------
__global__ __launch_bounds__(256) void k_convert(ConvArgs a, float* __restrict__ dst,
    const int* __restrict__ flag){
  int id = blockIdx.y;
  int i = blockIdx.x*256 + threadIdx.x;
  if (i >= a.n[id]) return;
  float v;
  if (*flag) v = bf2f(((const u16*)a.src[id])[i]);
  else       v = ((const float*)a.src[id])[i];
  dst[(size_t)a.off[id] + i] = v;
}

// ---------------- weights -> bf16 W^T staging: dst[lay*6+mat][n][k] = W[lay][k][n] ----
struct WPtrs { const void* p[6]; };
__global__ __launch_bounds__(256) void k_wt(WPtrs wp, u16* __restrict__ dst,
    const int* __restrict__ flag){
  int mz = blockIdx.z; int lay = mz / 6, mat = mz % 6;
  int n0 = blockIdx.x*64, k0 = blockIdx.y*64;
  int t = threadIdx.x; int r = t >> 6, c = t & 63;
  __shared__ u16 tile[64][65];   // tile[k_local][n_local]
  int isbf = *flag;
  const void* src = wp.p[mat];
  for (int rr = r; rr < 64; rr += 4){
    size_t idx = ((size_t)lay*DD + (k0+rr))*DD + n0 + c;
    u16 v;
    if (isbf) v = ((const u16*)src)[idx];
    else      v = f2b(((const float*)src)[idx]);
    tile[rr][c] = v;
  }
  __syncthreads();
  u16* drow = dst + ((size_t)mz*DD + n0)*DD + k0;
  for (int rr = r; rr < 64; rr += 4)
    drow[(size_t)rr*DD + c] = tile[c][rr];
}

// ---------------- embed ----------------
__global__ __launch_bounds__(256) void k_embed(const float* __restrict__ x, const float* __restrict__ w,
    const float* __restrict__ b, float* __restrict__ h, u16* __restrict__ hB){
  int i = blockIdx.x*256 + threadIdx.x;
  int d = i & (DD-1); int r = i >> 9;
  const float* xr = x + r*EE;
  float acc = b[d];
  #pragma unroll
  for (int e=0;e<EE;e++) acc = fmaf(xr[e], w[e*DD+d], acc);
  h[i] = acc;
  hB[i] = f2b(acc);
}

// ---------------- zero ksum/vsum (4096 floats) ----------------
__global__ void k_zero(float* __restrict__ p){
  p[blockIdx.x*256 + threadIdx.x] = 0.f;
}

// ---------------- MFMA GEMM (generic): C = A(bf16) @ Bt^T + bias ----------------
__global__ __launch_bounds__(256) void k_gemm_mfma(const u16* __restrict__ A, const u16* __restrict__ Bt,
    const float* __restrict__ bias, float* __restrict__ Cf, u16* __restrict__ Cb, int relu){
  __shared__ u16 As[128*64];
  __shared__ u16 Bs[128*64];
  int t = threadIdx.x, wave = t >> 6, lane = t & 63;
  int mb = blockIdx.y * 128, nb = blockIdx.x * 128;
  int wm = (wave & 1) * 64, wn = (wave >> 1) * 64;
  f32x4 acc[4][4];
  #pragma unroll
  for (int i=0;i<4;i++)
    #pragma unroll
    for (int j=0;j<4;j++) acc[i][j] = (f32x4){0.f,0.f,0.f,0.f};

  int srow = wave*8 + (lane>>3);
  int scol = (lane&7)*8;
  const u16* Ag = A + (size_t)(mb + srow)*DD + scol;
  const u16* Bg = Bt + (size_t)(nb + srow)*DD + scol;

  for (int k0 = 0; k0 < DD; k0 += 64){
    __syncthreads();
    #pragma unroll
    for (int i=0;i<4;i++){
      gld_lds16(Ag + (size_t)i*32*DD + k0, As + (i*32 + wave*8)*64);
      gld_lds16(Bg + (size_t)i*32*DD + k0, Bs + (i*32 + wave*8)*64);
    }
    __syncthreads();
    #pragma unroll
    for (int ch=0; ch<2; ++ch){
      bf16x8 af[4], bf[4];
      int kof = ch*32 + (lane>>4)*8;
      #pragma unroll
      for (int i=0;i<4;i++) af[i] = *(const bf16x8*)(As + (wm + i*16 + (lane&15))*64 + kof);
      #pragma unroll
      for (int j=0;j<4;j++) bf[j] = *(const bf16x8*)(Bs + (wn + j*16 + (lane&15))*64 + kof);
      #pragma unroll
      for (int i=0;i<4;i++)
        #pragma unroll
        for (int j=0;j<4;j++)
          acc[i][j] = __builtin_amdgcn_mfma_f32_16x16x32_bf16(af[i], bf[j], acc[i][j], 0, 0, 0);
    }
  }
  #pragma unroll
  for (int i=0;i<4;i++){
    int rbase = mb + wm + i*16 + (lane>>4)*4;
    #pragma unroll
    for (int j=0;j<4;j++){
      int col = nb + wn + j*16 + (lane&15);
      float bv = bias[col];
      #pragma unroll
      for (int r=0;r<4;r++){
        float cv = acc[i][j][r] + bv;
        if (relu) cv = fmaxf(cv, 0.f);
        size_t off = (size_t)(rbase + r)*DD + col;
        if (Cf) Cf[off] = cv;
        if (Cb) Cb[off] = f2b(cv);
      }
    }
  }
}

// ---------------- fused QKV GEMM + ksum/vsum epilogue ----------------
// grid (12, 64): nbg in [0,1536), sel = which of q/k/v
__global__ __launch_bounds__(256) void k_gemm_qkv(const u16* __restrict__ A, const u16* __restrict__ Wt,
    const float* __restrict__ bq, const float* __restrict__ bk, const float* __restrict__ bv,
    u16* __restrict__ qB, u16* __restrict__ kB, u16* __restrict__ vB,
    float* __restrict__ ksum, float* __restrict__ vsum){
  __shared__ u16 As[128*64];
  __shared__ u16 Bs[128*64];
  int t = threadIdx.x, wave = t >> 6, lane = t & 63;
  int nbg = blockIdx.x * 128;
  int sel = nbg >> 9;
  int nb  = nbg & 511;
  int mb  = blockIdx.y * 128;
  const float* bias = (sel==0) ? bq : (sel==1) ? bk : bv;
  u16* out = (sel==0) ? qB : (sel==1) ? kB : vB;
  const u16* Bt = Wt + (size_t)sel*DD*DD;
  int wm = (wave & 1) * 64, wn = (wave >> 1) * 64;
  f32x4 acc[4][4];
  #pragma unroll
  for (int i=0;i<4;i++)
    #pragma unroll
    for (int j=0;j<4;j++) acc[i][j] = (f32x4){0.f,0.f,0.f,0.f};

  int srow = wave*8 + (lane>>3);
  int scol = (lane&7)*8;
  const u16* Ag = A + (size_t)(mb + srow)*DD + scol;
  const u16* Bg = Bt + (size_t)(nb + srow)*DD + scol;

  for (int k0 = 0; k0 < DD; k0 += 64){
    __syncthreads();
    #pragma unroll
    for (int i=0;i<4;i++){
      gld_lds16(Ag + (size_t)i*32*DD + k0, As + (i*32 + wave*8)*64);
      gld_lds16(Bg + (size_t)i*32*DD + k0, Bs + (i*32 + wave*8)*64);
    }
    __syncthreads();
    #pragma unroll
    for (int ch=0; ch<2; ++ch){
      bf16x8 af[4], bf[4];
      int kof = ch*32 + (lane>>4)*8;
      #pragma unroll
      for (int i=0;i<4;i++) af[i] = *(const bf16x8*)(As + (wm + i*16 + (lane&15))*64 + kof);
      #pragma unroll
      for (int j=0;j<4;j++) bf[j] = *(const bf16x8*)(Bs + (wn + j*16 + (lane&15))*64 + kof);
      #pragma unroll
      for (int i=0;i<4;i++)
        #pragma unroll
        for (int j=0;j<4;j++)
          acc[i][j] = __builtin_amdgcn_mfma_f32_16x16x32_bf16(af[i], bf[j], acc[i][j], 0, 0, 0);
    }
  }
  float csum[4] = {0.f,0.f,0.f,0.f};
  #pragma unroll
  for (int j=0;j<4;j++){
    int col = nb + wn + j*16 + (lane&15);
    float bvv = bias[col];
    #pragma unroll
    for (int i=0;i<4;i++){
      int rbase = mb + wm + i*16 + (lane>>4)*4;
      #pragma unroll
      for (int r=0;r<4;r++){
        float cv = acc[i][j][r] + bvv;
        out[(size_t)(rbase + r)*DD + col] = f2b(cv);
        csum[j] += cv;
      }
    }
  }
  if (sel > 0){
    float* dst = (sel==1) ? ksum : vsum;
    int bidx = mb >> 11;          // batch index (2048 rows per batch)
    #pragma unroll
    for (int j=0;j<4;j++){
      float v = csum[j];
      v += __shfl_xor(v, 16);
      v += __shfl_xor(v, 32);
      if ((lane>>4) == 0)
        atomicAdd(dst + bidx*512 + nb + wn + j*16 + lane, v);
    }
  }
}

// ---------------- MFMA sparsity: M[q] = SCALE*(max_k q.k - (q.ksum)/L) ----------------
__global__ __launch_bounds__(256) void k_sparsity_mfma(const u16* __restrict__ qB, const u16* __restrict__ kB,
    const float* __restrict__ ksum, float* __restrict__ Mout){
  int bh = blockIdx.y; int b = bh >> 3, hh = bh & 7;
  int q0 = blockIdx.x * 64;
  int t = threadIdx.x, wave = t >> 6, lane = t & 63;
  const u16* qbase = qB + ((size_t)(b*LL + q0))*DD + hh*DHH;
  const u16* kbase = kB + ((size_t)b*LL)*DD + hh*DHH;
  bf16x8 qa[4][2];
  #pragma unroll
  for (int i=0;i<4;i++)
    #pragma unroll
    for (int c=0;c<2;c++)
      qa[i][c] = *(const bf16x8*)(qbase + (size_t)(i*16 + (lane&15))*DD + c*32 + (lane>>4)*8);
  float rmax[4][4];
  #pragma unroll
  for (int i=0;i<4;i++)
    #pragma unroll
    for (int r=0;r<4;r++) rmax[i][r] = -3.0e38f;
  for (int kt = wave*16; kt < LL; kt += 64){
    bf16x8 kb0 = *(const bf16x8*)(kbase + (size_t)(kt + (lane&15))*DD + (lane>>4)*8);
    bf16x8 kb1 = *(const bf16x8*)(kbase + (size_t)(kt + (lane&15))*DD + 32 + (lane>>4)*8);
    #pragma unroll
    for (int i=0;i<4;i++){
      f32x4 a = (f32x4){0.f,0.f,0.f,0.f};
      a = __builtin_amdgcn_mfma_f32_16x16x32_bf16(qa[i][0], kb0, a, 0, 0, 0);
      a = __builtin_amdgcn_mfma_f32_16x16x32_bf16(qa[i][1], kb1, a, 0, 0, 0);
      #pragma unroll
      for (int r=0;r<4;r++) rmax[i][r] = fmaxf(rmax[i][r], a[r]);
    }
  }
  #pragma unroll
  for (int i=0;i<4;i++)
    #pragma unroll
    for (int r=0;r<4;r++){
      float v = rmax[i][r];
      v = fmaxf(v, __shfl_xor(v, 1));
      v = fmaxf(v, __shfl_xor(v, 2));
      v = fmaxf(v, __shfl_xor(v, 4));
      v = fmaxf(v, __shfl_xor(v, 8));
      rmax[i][r] = v;
    }
  __shared__ float smax[4][64];
  if ((lane & 15) == 0){
    #pragma unroll
    for (int i=0;i<4;i++)
      #pragma unroll
      for (int r=0;r<4;r++)
        smax[wave][i*16 + (lane>>4)*4 + r] = rmax[i][r];
  }
  __syncthreads();
  if (t < 64){
    float mx = fmaxf(fmaxf(smax[0][t], smax[1][t]), fmaxf(smax[2][t], smax[3][t]));
    const u16* qrow = qB + (size_t)(b*LL + q0 + t)*DD + hh*DHH;
    float dot = 0.f;
    #pragma unroll 16
    for (int d=0; d<DHH; ++d) dot += bf2f(qrow[d]) * ksum[bh*DHH + d];
    Mout[bh*LL + q0 + t] = SCALE * (mx - dot * (1.0f/LL));
  }
}

// ---------------- top-U selection (stable: ties -> smaller index) ----------------
__global__ __launch_bounds__(256) void k_topk(const float* __restrict__ M, int* __restrict__ sidx){
  int bh = blockIdx.x; int t = threadIdx.x;
  __shared__ float vals[LL];
  __shared__ float rv[256]; __shared__ int ri[256];
  for (int j = t; j < LL; j += 256) vals[j] = M[bh*LL + j];
  __syncthreads();
  for (int it = 0; it < UU; ++it){
    float best = -3.0e38f; int barg = LL;
    for (int j = t; j < LL; j += 256){
      float v = vals[j];
      if (v > best){ best = v; barg = j; }
    }
    rv[t]=best; ri[t]=barg;
    __syncthreads();
    for (int s=128; s>0; s>>=1){
      if (t < s){
        float v2 = rv[t+s]; int i2 = ri[t+s];
        if (v2 > rv[t] || (v2 == rv[t] && i2 < ri[t])){ rv[t]=v2; ri[t]=i2; }
      }
      __syncthreads();
    }
    if (t == 0){ sidx[bh*UU + it] = ri[0]; vals[ri[0]] = -3.4e38f; }
    __syncthreads();
  }
}

// ---------------- ctx default = vsum/L broadcast (bf16) ----------------
__global__ __launch_bounds__(256) void k_fill_ctx(const float* __restrict__ vsum, u16* __restrict__ ctxB){
  int i = blockIdx.x*256 + threadIdx.x;
  int c = i & (DD-1);
  int b = i >> 20;               // L*D = 2^20
  ctxB[i] = f2b(vsum[(b << 9) + c] * (1.0f/LL));
}

// ---------------- flash attention partial: per (bh, key-chunk) ----------------
// Q_sel[48x64] @ K_chunk^T -> local softmax partials -> P @ V_chunk
__global__ __launch_bounds__(256) void k_flash(const u16* __restrict__ qB, const u16* __restrict__ kB,
    const u16* __restrict__ vB, const int* __restrict__ sidx,
    float* __restrict__ pO, float* __restrict__ pM, float* __restrict__ pS){
  int bh = blockIdx.y, c = blockIdx.x;
  int b = bh >> 3, hh = bh & 7;
  int t = threadIdx.x, w = t >> 6, lane = t & 63;
  int qlane = lane & 15, quad = lane >> 4;
  int l0 = c * FCH;
  __shared__ u16 Ps[48*PSTR];
  __shared__ u16 VsT[64*VSTR];
  __shared__ float wred[4][48];
  __shared__ float mrow[48];
  const u16* kbase = kB + (size_t)b*LL*DD + hh*DHH;
  const u16* vbase = vB + (size_t)b*LL*DD + hh*DHH;
  const u16* qbase = qB + (size_t)b*LL*DD + hh*DHH;

  // Q fragments (rows >= UU zeroed)
  bf16x8 qa[3][2];
  #pragma unroll
  for (int i=0;i<3;i++){
    int u = i*16 + qlane;
    if (u < UU){
      const u16* qr = qbase + (size_t)sidx[bh*UU + u]*DD + quad*8;
      qa[i][0] = *(const bf16x8*)qr;
      qa[i][1] = *(const bf16x8*)(qr + 32);
    } else {
      bf16x8 z;
      #pragma unroll
      for (int q8=0;q8<8;q8++) z[q8] = (__bf16)0.0f;
      qa[i][0] = z; qa[i][1] = z;
    }
  }
  // S = scale * Q K^T : wave w covers keys [l0+w*64, +64)
  f32x4 S[3][4];
  #pragma unroll
  for (int j=0;j<4;j++){
    const u16* kr = kbase + (size_t)(l0 + w*64 + j*16 + qlane)*DD + quad*8;
    bf16x8 k0 = *(const bf16x8*)kr;
    bf16x8 k1 = *(const bf16x8*)(kr + 32);
    #pragma unroll
    for (int i=0;i<3;i++){
      f32x4 a = (f32x4){0.f,0.f,0.f,0.f};
      a = __builtin_amdgcn_mfma_f32_16x16x32_bf16(qa[i][0], k0, a, 0, 0, 0);
      a = __builtin_amdgcn_mfma_f32_16x16x32_bf16(qa[i][1], k1, a, 0, 0, 0);
      S[i][j] = a;
    }
  }
  // scale + wave-local row max
  #pragma unroll
  for (int i=0;i<3;i++){
    #pragma unroll
    for (int r=0;r<4;r++){
      float m = -3.0e38f;
      #pragma unroll
      for (int j=0;j<4;j++){ S[i][j][r] *= SCALE; m = fmaxf(m, S[i][j][r]); }
      m = fmaxf(m, __shfl_xor(m, 1));
      m = fmaxf(m, __shfl_xor(m, 2));
      m = fmaxf(m, __shfl_xor(m, 4));
      m = fmaxf(m, __shfl_xor(m, 8));
      if (qlane == 0) wred[w][i*16 + quad*4 + r] = m;
    }
  }
  __syncthreads();
  if (t < 48) mrow[t] = fmaxf(fmaxf(wred[0][t], wred[1][t]), fmaxf(wred[2][t], wred[3][t]));
  __syncthreads();
  // P = exp(S - m) -> Ps (bf16, C-layout scatter); local row sums
  #pragma unroll
  for (int i=0;i<3;i++){
    #pragma unroll
    for (int r=0;r<4;r++){
      int row = i*16 + quad*4 + r;
      float m = mrow[row];
      float ls = 0.f;
      #pragma unroll
      for (int j=0;j<4;j++){
        float e = __expf(S[i][j][r] - m);
        ls += e;
        Ps[row*PSTR + w*64 + j*16 + qlane] = f2b(e);
      }
      ls += __shfl_xor(ls, 1);
      ls += __shfl_xor(ls, 2);
      ls += __shfl_xor(ls, 4);
      ls += __shfl_xor(ls, 8);
      if (qlane == 0) wred[w][row] = ls;
    }
  }
  __syncthreads();
  if (t < 48){
    pM[(bh*NCH + c)*48 + t] = mrow[t];
    pS[(bh*NCH + c)*48 + t] = wred[0][t] + wred[1][t] + wred[2][t] + wred[3][t];
  }
  // O = P @ V  (wave w -> output cols w*16..w*16+15)
  f32x4 O[3];
  #pragma unroll
  for (int i=0;i<3;i++) O[i] = (f32x4){0.f,0.f,0.f,0.f};
  for (int half = 0; half < 2; ++half){
    __syncthreads();     // protect VsT (and Ps on first pass)
    for (int idx = t; idx < 128*64; idx += 256){
      int rr = idx >> 6, d = idx & 63;
      VsT[d*VSTR + rr] = vbase[(size_t)(l0 + half*128 + rr)*DD + d];
    }
    __syncthreads();
    #pragma unroll
    for (int ks = 0; ks < 4; ++ks){
      int kloc = half*128 + ks*32;
      bf16x8 bfv = *(const bf16x8*)(VsT + (w*16 + qlane)*VSTR + ks*32 + quad*8);
      #pragma unroll
      for (int i=0;i<3;i++){
        bf16x8 af = *(const bf16x8*)(Ps + (i*16 + qlane)*PSTR + kloc + quad*8);
        O[i] = __builtin_amdgcn_mfma_f32_16x16x32_bf16(af, bfv, O[i], 0, 0, 0);
      }
    }
  }
  size_t ob = (size_t)(bh*NCH + c)*48*64;
  #pragma unroll
  for (int i=0;i<3;i++)
    #pragma unroll
    for (int r=0;r<4;r++)
      pO[ob + (size_t)(i*16 + quad*4 + r)*64 + w*16 + qlane] = O[i][r];
}

// ---------------- flash combine: merge chunk partials, scatter into ctxB ----------------
__global__ __launch_bounds__(256) void k_flash_red(const float* __restrict__ pO, const float* __restrict__ pM,
    const float* __restrict__ pS, const int* __restrict__ sidx, u16* __restrict__ ctxB){
  int bh = blockIdx.x; int b = bh >> 3, hh = bh & 7;
  int t = threadIdx.x;
  for (int idx = t; idx < UU*64; idx += 256){
    int u = idx >> 6, n = idx & 63;
    float m = -3.0e38f;
    #pragma unroll
    for (int c=0;c<NCH;c++) m = fmaxf(m, pM[(bh*NCH + c)*48 + u]);
    float s = 0.f, o = 0.f;
    #pragma unroll
    for (int c=0;c<NCH;c++){
      float wgt = __expf(pM[(bh*NCH + c)*48 + u] - m);
      s += wgt * pS[(bh*NCH + c)*48 + u];
      o += wgt * pO[((size_t)(bh*NCH + c)*48 + u)*64 + n];
    }
    int qrow = sidx[bh*UU + u];
    ctxB[(size_t)(b*LL + qrow)*DD + hh*DHH + n] = f2b(o / s);
  }
}

// ---------------- out = LayerNorm(a + r) * g + b (fp32 out + bf16 out) ----------------
__global__ __launch_bounds__(256) void k_addln(const float* __restrict__ a, const float* __restrict__ r,
    const float* __restrict__ g, const float* __restrict__ bvec, float* __restrict__ out,
    u16* __restrict__ outB){
  int row = blockIdx.x; int t = threadIdx.x;
  size_t base = (size_t)row * DD;
  float v0 = a[base+t] + r[base+t];
  float v1 = a[base+t+256] + r[base+t+256];
  __shared__ float red[256];
  red[t] = v0+v1; __syncthreads();
  for (int s=128;s>0;s>>=1){ if (t<s) red[t]+=red[t+s]; __syncthreads(); }
  float mean = red[0] * (1.0f/DD);
  __syncthreads();
  float d0 = v0-mean, d1 = v1-mean;
  red[t] = d0*d0 + d1*d1; __syncthreads();
  for (int s=128;s>0;s>>=1){ if (t<s) red[t]+=red[t+s]; __syncthreads(); }
  float rs = rsqrtf(red[0]*(1.0f/DD) + 1e-5f);
  float o0 = d0*rs*g[t]     + bvec[t];
  float o1 = d1*rs*g[t+256] + bvec[t+256];
  out[base+t] = o0;       out[base+t+256] = o1;
  outB[base+t] = f2b(o0); outB[base+t+256] = f2b(o1);
}

// ---------------- final projection ----------------
__global__ __launch_bounds__(64) void k_proj(const float* __restrict__ h, const float* __restrict__ pw,
    const float* __restrict__ pb, void* __restrict__ out, const int* __restrict__ flag){
  int rp = blockIdx.x; int b = rp / PP, pp = rp % PP;
  int t = threadIdx.x;
  const float* hr = h + (size_t)(b*LL + (LL-PP) + pp) * DD;
  float acc[EE];
  #pragma unroll
  for (int e=0;e<EE;e++) acc[e]=0.f;
  for (int d = t; d < DD; d += 64){
    float hv = hr[d];
    #pragma unroll
    for (int e=0;e<EE;e++) acc[e] = fmaf(hv, pw[d*EE+e], acc[e]);
  }
  int isbf = *flag;
  #pragma unroll
  for (int e=0;e<EE;e++){
    float rr = acc[e];
    for (int off=32; off>0; off>>=1) rr += __shfl_down(rr, off);
    if (t == 0){
      float val = rr + pb[e];
      if (isbf) ((__hip_bfloat16*)out)[(size_t)rp*EE + e] = __float2bfloat16(val);
      else      ((float*)out)[(size_t)rp*EE + e] = val;
    }
  }
}

extern "C" void kernel_launch(void* const* d_in, const int* in_sizes, int n_in,
                              void* d_out, int out_size, void* d_ws, size_t ws_size,
                              hipStream_t stream){
  float* ws    = (float*)d_ws;
  float* h     = ws;                                  // BIGN
  float* Mv    = ws + BIGN;                           // 65536
  float* ksum  = Mv + (size_t)BB*HH*LL;               // 2048
  float* vsum  = ksum + 2048;                         // 2048 (contiguous after ksum!)
  float* pM    = vsum + 2048;                         // 32*8*48 = 12288
  float* pS    = pM + 12288;                          // 12288
  float* pO    = pS + 12288;                          // 32*8*48*64 = 786432
  float* tmpF  = pO + 786432;                         // BIGN (attn out / ffn out)
  int*   sidx  = (int*)(tmpF + BIGN);                 // 1280
  int*   flag  = sidx + 1280;
  u16*   hB    = (u16*)(flag + 4);
  u16*   qB    = hB + BIGN;
  u16*   kB    = qB + BIGN;
  u16*   vB    = kB + BIGN;
  u16*   ctxB  = vB + BIGN;
  u16*   f1B   = ctxB + BIGN;
  u16*   wT    = f1B + BIGN;                          // 12*512*512 u16
  float* conv  = (float*)(wT + (size_t)12*DD*DD);

  static const int small_ids[NSMALL] = {0,1,2,4,6,8,10,12,14,15,16,17,18,19,20};
  ConvArgs ca;
  int off_all[NIN];
  int tot = 0, maxn = 0;
  for (int i = 0; i < NIN; ++i) off_all[i] = -1;
  for (int s = 0; s < NSMALL; ++s){
    int i = small_ids[s];
    ca.src[s] = d_in[i];
    ca.off[s] = tot;
    ca.n[s]   = in_sizes[i];
    off_all[i] = tot;
    tot += in_sizes[i];
    if (in_sizes[i] > maxn) maxn = in_sizes[i];
  }
  const float* x     = conv + off_all[0];
  const float* emb_w = conv + off_all[1];
  const float* emb_b = conv + off_all[2];
  const float* bq = conv + off_all[4];
  const float* bk = conv + off_all[6];
  const float* bv = conv + off_all[8];
  const float* bo = conv + off_all[10];
  const float* b1 = conv + off_all[12];
  const float* b2 = conv + off_all[14];
  const float* ln1g = conv + off_all[15]; const float* ln1b = conv + off_all[16];
  const float* ln2g = conv + off_all[17]; const float* ln2b = conv + off_all[18];
  const float* pw = conv + off_all[19]; const float* pb = conv + off_all[20];

  WPtrs wp;
  wp.p[0]=d_in[3]; wp.p[1]=d_in[5]; wp.p[2]=d_in[7];
  wp.p[3]=d_in[9]; wp.p[4]=d_in[11]; wp.p[5]=d_in[13];

  k_probe<<<1, 64, 0, stream>>>(d_in[15], flag);
  k_convert<<<dim3((maxn + 255)/256, NSMALL), 256, 0, stream>>>(ca, conv, flag);
  k_wt<<<dim3(8, 8, 12), 256, 0, stream>>>(wp, wT, flag);

  dim3 gg(DD/128, ROWS/128);     // (4,64)
  dim3 gq(3*DD/128, ROWS/128);   // (12,64) fused QKV

  k_embed<<<ROWS*DD/256, 256, 0, stream>>>(x, emb_w, emb_b, h, hB);
  for (int l = 0; l < NLAYER; ++l){
    const u16* WqkvT = wT + (size_t)(l*6 + 0)*DD*DD;   // q,k,v contiguous
    const u16* WoT   = wT + (size_t)(l*6 + 3)*DD*DD;
    const u16* W1T   = wT + (size_t)(l*6 + 4)*DD*DD;
    const u16* W2T   = wT + (size_t)(l*6 + 5)*DD*DD;

    k_zero<<<16, 256, 0, stream>>>(ksum);   // zeroes ksum+vsum (4096 floats)
    k_gemm_qkv<<<gq, 256, 0, stream>>>(hB, WqkvT, bq + l*DD, bk + l*DD, bv + l*DD,
                                       qB, kB, vB, ksum, vsum);
    k_sparsity_mfma<<<dim3(LL/64, BB*HH), 256, 0, stream>>>(qB, kB, ksum, Mv);
    k_topk<<<BB*HH, 256, 0, stream>>>(Mv, sidx);
    k_fill_ctx<<<ROWS*DD/256, 256, 0, stream>>>(vsum, ctxB);
    k_flash<<<dim3(NCH, BB*HH), 256, 0, stream>>>(qB, kB, vB, sidx, pO, pM, pS);
    k_flash_red<<<BB*HH, 256, 0, stream>>>(pO, pM, pS, sidx, ctxB);
    k_gemm_mfma<<<gg, 256, 0, stream>>>(ctxB, WoT, bo + l*DD, tmpF, nullptr, 0);
    k_addln<<<ROWS, 256, 0, stream>>>(h, tmpF, ln1g + l*DD, ln1b + l*DD, h, hB);
    k_gemm_mfma<<<gg, 256, 0, stream>>>(hB, W1T, b1 + l*DD, nullptr, f1B, 1);
    k_gemm_mfma<<<gg, 256, 0, stream>>>(f1B, W2T, b2 + l*DD, tmpF, nullptr, 0);
    k_addln<<<ROWS, 256, 0, stream>>>(h, tmpF, ln2g + l*DD, ln2b + l*DD, h, hB);
  }
  k_proj<<<BB*PP, 64, 0, stream>>>(h, pw, pb, d_out, flag);
}

// Round 5
// 564.788 us; speedup vs baseline: 4.5329x; 1.0416x over previous
//
#include <hip/hip_runtime.h>
#include <hip/hip_bf16.h>
#include <cstdint>
#include <cstddef>

// Problem dims
#define BB 4
#define LL 2048
#define EE 7
#define DD 512
#define HH 8
#define DHH 64
#define PP 720
#define NLAYER 2
#define UU 40
#define SCALE 0.125f
#define ROWS (BB*LL)                  // 8192
#define BIGN ((size_t)ROWS*DD)        // 4194304 elements per big buffer
#define NIN 21
#define FCH 256                       // flash keys per chunk
#define NCH (LL/FCH)                  // 8
#define PSTR 264                      // Ps row stride (u16)
#define VSTR 136                      // VsT row stride (u16)

typedef unsigned short u16;
typedef __bf16 bf16x8 __attribute__((ext_vector_type(8)));
typedef float  f32x4  __attribute__((ext_vector_type(4)));

__device__ __forceinline__ float bf2f(u16 u){
  union { uint32_t i; float f; } c; c.i = ((uint32_t)u) << 16; return c.f;
}
__device__ __forceinline__ u16 f2b(float f){
  __hip_bfloat16 h = __float2bfloat16(f);
  return *(u16*)&h;
}
__device__ __forceinline__ void gld_lds16(const u16* g, u16* l){
  __builtin_amdgcn_global_load_lds(
      (const __attribute__((address_space(1))) uint32_t*)g,
      (__attribute__((address_space(3))) uint32_t*)l, 16, 0, 0);
}

// ---------------- dtype probe: ln1_g[0] == 1.0 ----------------
__global__ void k_probe(const void* __restrict__ g, int* __restrict__ flag){
  if (threadIdx.x == 0 && blockIdx.x == 0){
    uint32_t bits = *(const uint32_t*)g;
    *flag = (bits == 0x3F800000u) ? 0 : 1;   // 1 = bf16 inputs
  }
}

#define NSMALL 15
struct ConvArgs { const void* src[NSMALL]; int off[NSMALL]; int n[NSMALL]; };

// ---------------- convert small inputs to fp32 staging ----------------
__global__ __launch_bounds__(256) void k_convert(ConvArgs a, float* __restrict__ dst,
    const int* __restrict__ flag){
  int id = blockIdx.y;
  int i = blockIdx.x*256 + threadIdx.x;
  if (i >= a.n[id]) return;
  float v;
  if (*flag) v = bf2f(((const u16*)a.src[id])[i]);
  else       v = ((const float*)a.src[id])[i];
  dst[(size_t)a.off[id] + i] = v;
}

// ---------------- weights -> bf16 W^T staging: dst[lay*6+mat][n][k] = W[lay][k][n] ----
struct WPtrs { const void* p[6]; };
__global__ __launch_bounds__(256) void k_wt(WPtrs wp, u16* __restrict__ dst,
    const int* __restrict__ flag){
  int mz = blockIdx.z; int lay = mz / 6, mat = mz % 6;
  int n0 = blockIdx.x*64, k0 = blockIdx.y*64;
  int t = threadIdx.x; int r = t >> 6, c = t & 63;
  __shared__ u16 tile[64][65];   // tile[k_local][n_local]
  int isbf = *flag;
  const void* src = wp.p[mat];
  for (int rr = r; rr < 64; rr += 4){
    size_t idx = ((size_t)lay*DD + (k0+rr))*DD + n0 + c;
    u16 v;
    if (isbf) v = ((const u16*)src)[idx];
    else      v = f2b(((const float*)src)[idx]);
    tile[rr][c] = v;
  }
  __syncthreads();
  u16* drow = dst + ((size_t)mz*DD + n0)*DD + k0;
  for (int rr = r; rr < 64; rr += 4)
    drow[(size_t)rr*DD + c] = tile[c][rr];
}

// ---------------- embed ----------------
__global__ __launch_bounds__(256) void k_embed(const float* __restrict__ x, const float* __restrict__ w,
    const float* __restrict__ b, float* __restrict__ h, u16* __restrict__ hB){
  int i = blockIdx.x*256 + threadIdx.x;
  int d = i & (DD-1); int r = i >> 9;
  const float* xr = x + r*EE;
  float acc = b[d];
  #pragma unroll
  for (int e=0;e<EE;e++) acc = fmaf(xr[e], w[e*DD+d], acc);
  h[i] = acc;
  hB[i] = f2b(acc);
}

// ---------------- zero ksum/vsum (4096 floats) ----------------
__global__ void k_zero(float* __restrict__ p){
  p[blockIdx.x*256 + threadIdx.x] = 0.f;
}

// ---------------- MFMA GEMM (generic): C = A(bf16) @ Bt^T + bias ----------------
__global__ __launch_bounds__(256) void k_gemm_mfma(const u16* __restrict__ A, const u16* __restrict__ Bt,
    const float* __restrict__ bias, float* __restrict__ Cf, u16* __restrict__ Cb, int relu){
  __shared__ u16 As[128*64];
  __shared__ u16 Bs[128*64];
  int t = threadIdx.x, wave = t >> 6, lane = t & 63;
  int mb = blockIdx.y * 128, nb = blockIdx.x * 128;
  int wm = (wave & 1) * 64, wn = (wave >> 1) * 64;
  f32x4 acc[4][4];
  #pragma unroll
  for (int i=0;i<4;i++)
    #pragma unroll
    for (int j=0;j<4;j++) acc[i][j] = (f32x4){0.f,0.f,0.f,0.f};

  int srow = wave*8 + (lane>>3);
  int scol = (lane&7)*8;
  const u16* Ag = A + (size_t)(mb + srow)*DD + scol;
  const u16* Bg = Bt + (size_t)(nb + srow)*DD + scol;

  for (int k0 = 0; k0 < DD; k0 += 64){
    __syncthreads();
    #pragma unroll
    for (int i=0;i<4;i++){
      gld_lds16(Ag + (size_t)i*32*DD + k0, As + (i*32 + wave*8)*64);
      gld_lds16(Bg + (size_t)i*32*DD + k0, Bs + (i*32 + wave*8)*64);
    }
    __syncthreads();
    #pragma unroll
    for (int ch=0; ch<2; ++ch){
      bf16x8 af[4], bf[4];
      int kof = ch*32 + (lane>>4)*8;
      #pragma unroll
      for (int i=0;i<4;i++) af[i] = *(const bf16x8*)(As + (wm + i*16 + (lane&15))*64 + kof);
      #pragma unroll
      for (int j=0;j<4;j++) bf[j] = *(const bf16x8*)(Bs + (wn + j*16 + (lane&15))*64 + kof);
      #pragma unroll
      for (int i=0;i<4;i++)
        #pragma unroll
        for (int j=0;j<4;j++)
          acc[i][j] = __builtin_amdgcn_mfma_f32_16x16x32_bf16(af[i], bf[j], acc[i][j], 0, 0, 0);
    }
  }
  #pragma unroll
  for (int i=0;i<4;i++){
    int rbase = mb + wm + i*16 + (lane>>4)*4;
    #pragma unroll
    for (int j=0;j<4;j++){
      int col = nb + wn + j*16 + (lane&15);
      float bv = bias[col];
      #pragma unroll
      for (int r=0;r<4;r++){
        float cv = acc[i][j][r] + bv;
        if (relu) cv = fmaxf(cv, 0.f);
        size_t off = (size_t)(rbase + r)*DD + col;
        if (Cf) Cf[off] = cv;
        if (Cb) Cb[off] = f2b(cv);
      }
    }
  }
}

// ---------------- fused QKV GEMM + ksum/vsum epilogue ----------------
__global__ __launch_bounds__(256) void k_gemm_qkv(const u16* __restrict__ A, const u16* __restrict__ Wt,
    const float* __restrict__ bq, const float* __restrict__ bk, const float* __restrict__ bv,
    u16* __restrict__ qB, u16* __restrict__ kB, u16* __restrict__ vB,
    float* __restrict__ ksum, float* __restrict__ vsum){
  __shared__ u16 As[128*64];
  __shared__ u16 Bs[128*64];
  int t = threadIdx.x, wave = t >> 6, lane = t & 63;
  int nbg = blockIdx.x * 128;
  int sel = nbg >> 9;
  int nb  = nbg & 511;
  int mb  = blockIdx.y * 128;
  const float* bias = (sel==0) ? bq : (sel==1) ? bk : bv;
  u16* out = (sel==0) ? qB : (sel==1) ? kB : vB;
  const u16* Bt = Wt + (size_t)sel*DD*DD;
  int wm = (wave & 1) * 64, wn = (wave >> 1) * 64;
  f32x4 acc[4][4];
  #pragma unroll
  for (int i=0;i<4;i++)
    #pragma unroll
    for (int j=0;j<4;j++) acc[i][j] = (f32x4){0.f,0.f,0.f,0.f};

  int srow = wave*8 + (lane>>3);
  int scol = (lane&7)*8;
  const u16* Ag = A + (size_t)(mb + srow)*DD + scol;
  const u16* Bg = Bt + (size_t)(nb + srow)*DD + scol;

  for (int k0 = 0; k0 < DD; k0 += 64){
    __syncthreads();
    #pragma unroll
    for (int i=0;i<4;i++){
      gld_lds16(Ag + (size_t)i*32*DD + k0, As + (i*32 + wave*8)*64);
      gld_lds16(Bg + (size_t)i*32*DD + k0, Bs + (i*32 + wave*8)*64);
    }
    __syncthreads();
    #pragma unroll
    for (int ch=0; ch<2; ++ch){
      bf16x8 af[4], bf[4];
      int kof = ch*32 + (lane>>4)*8;
      #pragma unroll
      for (int i=0;i<4;i++) af[i] = *(const bf16x8*)(As + (wm + i*16 + (lane&15))*64 + kof);
      #pragma unroll
      for (int j=0;j<4;j++) bf[j] = *(const bf16x8*)(Bs + (wn + j*16 + (lane&15))*64 + kof);
      #pragma unroll
      for (int i=0;i<4;i++)
        #pragma unroll
        for (int j=0;j<4;j++)
          acc[i][j] = __builtin_amdgcn_mfma_f32_16x16x32_bf16(af[i], bf[j], acc[i][j], 0, 0, 0);
    }
  }
  float csum[4] = {0.f,0.f,0.f,0.f};
  #pragma unroll
  for (int j=0;j<4;j++){
    int col = nb + wn + j*16 + (lane&15);
    float bvv = bias[col];
    #pragma unroll
    for (int i=0;i<4;i++){
      int rbase = mb + wm + i*16 + (lane>>4)*4;
      #pragma unroll
      for (int r=0;r<4;r++){
        float cv = acc[i][j][r] + bvv;
        out[(size_t)(rbase + r)*DD + col] = f2b(cv);
        csum[j] += cv;
      }
    }
  }
  if (sel > 0){
    float* dst = (sel==1) ? ksum : vsum;
    int bidx = mb >> 11;          // batch index (2048 rows per batch)
    #pragma unroll
    for (int j=0;j<4;j++){
      float v = csum[j];
      v += __shfl_xor(v, 16);
      v += __shfl_xor(v, 32);
      if ((lane>>4) == 0)
        atomicAdd(dst + bidx*512 + nb + wn + j*16 + lane, v);
    }
  }
}

// ---------------- MFMA sparsity: M[q] = SCALE*(max_k q.k - (q.ksum)/L) ----------------
__global__ __launch_bounds__(256) void k_sparsity_mfma(const u16* __restrict__ qB, const u16* __restrict__ kB,
    const float* __restrict__ ksum, float* __restrict__ Mout){
  int bh = blockIdx.y; int b = bh >> 3, hh = bh & 7;
  int q0 = blockIdx.x * 64;
  int t = threadIdx.x, wave = t >> 6, lane = t & 63;
  const u16* qbase = qB + ((size_t)(b*LL + q0))*DD + hh*DHH;
  const u16* kbase = kB + ((size_t)b*LL)*DD + hh*DHH;
  bf16x8 qa[4][2];
  #pragma unroll
  for (int i=0;i<4;i++)
    #pragma unroll
    for (int c=0;c<2;c++)
      qa[i][c] = *(const bf16x8*)(qbase + (size_t)(i*16 + (lane&15))*DD + c*32 + (lane>>4)*8);
  float rmax[4][4];
  #pragma unroll
  for (int i=0;i<4;i++)
    #pragma unroll
    for (int r=0;r<4;r++) rmax[i][r] = -3.0e38f;
  for (int kt = wave*16; kt < LL; kt += 64){
    bf16x8 kb0 = *(const bf16x8*)(kbase + (size_t)(kt + (lane&15))*DD + (lane>>4)*8);
    bf16x8 kb1 = *(const bf16x8*)(kbase + (size_t)(kt + (lane&15))*DD + 32 + (lane>>4)*8);
    #pragma unroll
    for (int i=0;i<4;i++){
      f32x4 a = (f32x4){0.f,0.f,0.f,0.f};
      a = __builtin_amdgcn_mfma_f32_16x16x32_bf16(qa[i][0], kb0, a, 0, 0, 0);
      a = __builtin_amdgcn_mfma_f32_16x16x32_bf16(qa[i][1], kb1, a, 0, 0, 0);
      #pragma unroll
      for (int r=0;r<4;r++) rmax[i][r] = fmaxf(rmax[i][r], a[r]);
    }
  }
  #pragma unroll
  for (int i=0;i<4;i++)
    #pragma unroll
    for (int r=0;r<4;r++){
      float v = rmax[i][r];
      v = fmaxf(v, __shfl_xor(v, 1));
      v = fmaxf(v, __shfl_xor(v, 2));
      v = fmaxf(v, __shfl_xor(v, 4));
      v = fmaxf(v, __shfl_xor(v, 8));
      rmax[i][r] = v;
    }
  __shared__ float smax[4][64];
  if ((lane & 15) == 0){
    #pragma unroll
    for (int i=0;i<4;i++)
      #pragma unroll
      for (int r=0;r<4;r++)
        smax[wave][i*16 + (lane>>4)*4 + r] = rmax[i][r];
  }
  __syncthreads();
  if (t < 64){
    float mx = fmaxf(fmaxf(smax[0][t], smax[1][t]), fmaxf(smax[2][t], smax[3][t]));
    const u16* qrow = qB + (size_t)(b*LL + q0 + t)*DD + hh*DHH;
    float dot = 0.f;
    #pragma unroll 16
    for (int d=0; d<DHH; ++d) dot += bf2f(qrow[d]) * ksum[bh*DHH + d];
    Mout[bh*LL + q0 + t] = SCALE * (mx - dot * (1.0f/LL));
  }
}

// ---------------- top-U: one wave per (b,h), all-register, no barriers ----------------
// Same semantics as np top_k: descending values, ties -> smaller index.
__global__ __launch_bounds__(64) void k_topk(const float* __restrict__ M, int* __restrict__ sidx){
  int bh = blockIdx.x; int lane = threadIdx.x;
  const float* src = M + (size_t)bh*LL + lane*32;
  float v[32];
  #pragma unroll
  for (int i=0;i<8;i++){
    float4 x4 = *(const float4*)(src + i*4);
    v[i*4+0]=x4.x; v[i*4+1]=x4.y; v[i*4+2]=x4.z; v[i*4+3]=x4.w;
  }
  unsigned int taken = 0u;
  for (int it = 0; it < UU; ++it){
    float best = -3.4e38f; int bidx = 0x7FFFFFFF;
    #pragma unroll
    for (int i=0;i<32;i++){
      float vv = ((taken>>i)&1u) ? -3.4e38f : v[i];
      if (vv > best){ best = vv; bidx = lane*32 + i; }   // ascending i: smallest idx on tie
    }
    #pragma unroll
    for (int off=1; off<64; off<<=1){
      float ov = __shfl_xor(best, off);
      int   oi = __shfl_xor(bidx, off);
      if (ov > best || (ov == best && oi < bidx)){ best = ov; bidx = oi; }
    }
    if ((bidx >> 5) == lane) taken |= 1u << (bidx & 31);
    if (lane == 0) sidx[bh*UU + it] = bidx;
  }
}

// ---------------- ctx default = vsum/L broadcast (bf16) ----------------
__global__ __launch_bounds__(256) void k_fill_ctx(const float* __restrict__ vsum, u16* __restrict__ ctxB){
  int i = blockIdx.x*256 + threadIdx.x;
  int c = i & (DD-1);
  int b = i >> 20;               // L*D = 2^20
  ctxB[i] = f2b(vsum[(b << 9) + c] * (1.0f/LL));
}

// ---------------- flash attention partial: per (bh, key-chunk) ----------------
__global__ __launch_bounds__(256) void k_flash(const u16* __restrict__ qB, const u16* __restrict__ kB,
    const u16* __restrict__ vB, const int* __restrict__ sidx,
    float* __restrict__ pO, float* __restrict__ pM, float* __restrict__ pS){
  int bh = blockIdx.y, c = blockIdx.x;
  int b = bh >> 3, hh = bh & 7;
  int t = threadIdx.x, w = t >> 6, lane = t & 63;
  int qlane = lane & 15, quad = lane >> 4;
  int l0 = c * FCH;
  __shared__ u16 Ps[48*PSTR];
  __shared__ u16 VsT[64*VSTR];
  __shared__ float wred[4][48];
  __shared__ float mrow[48];
  const u16* kbase = kB + (size_t)b*LL*DD + hh*DHH;
  const u16* vbase = vB + (size_t)b*LL*DD + hh*DHH;
  const u16* qbase = qB + (size_t)b*LL*DD + hh*DHH;

  bf16x8 qa[3][2];
  #pragma unroll
  for (int i=0;i<3;i++){
    int u = i*16 + qlane;
    if (u < UU){
      const u16* qr = qbase + (size_t)sidx[bh*UU + u]*DD + quad*8;
      qa[i][0] = *(const bf16x8*)qr;
      qa[i][1] = *(const bf16x8*)(qr + 32);
    } else {
      bf16x8 z;
      #pragma unroll
      for (int q8=0;q8<8;q8++) z[q8] = (__bf16)0.0f;
      qa[i][0] = z; qa[i][1] = z;
    }
  }
  f32x4 S[3][4];
  #pragma unroll
  for (int j=0;j<4;j++){
    const u16* kr = kbase + (size_t)(l0 + w*64 + j*16 + qlane)*DD + quad*8;
    bf16x8 k0 = *(const bf16x8*)kr;
    bf16x8 k1 = *(const bf16x8*)(kr + 32);
    #pragma unroll
    for (int i=0;i<3;i++){
      f32x4 a = (f32x4){0.f,0.f,0.f,0.f};
      a = __builtin_amdgcn_mfma_f32_16x16x32_bf16(qa[i][0], k0, a, 0, 0, 0);
      a = __builtin_amdgcn_mfma_f32_16x16x32_bf16(qa[i][1], k1, a, 0, 0, 0);
      S[i][j] = a;
    }
  }
  #pragma unroll
  for (int i=0;i<3;i++){
    #pragma unroll
    for (int r=0;r<4;r++){
      float m = -3.0e38f;
      #pragma unroll
      for (int j=0;j<4;j++){ S[i][j][r] *= SCALE; m = fmaxf(m, S[i][j][r]); }
      m = fmaxf(m, __shfl_xor(m, 1));
      m = fmaxf(m, __shfl_xor(m, 2));
      m = fmaxf(m, __shfl_xor(m, 4));
      m = fmaxf(m, __shfl_xor(m, 8));
      if (qlane == 0) wred[w][i*16 + quad*4 + r] = m;
    }
  }
  __syncthreads();
  if (t < 48) mrow[t] = fmaxf(fmaxf(wred[0][t], wred[1][t]), fmaxf(wred[2][t], wred[3][t]));
  __syncthreads();
  #pragma unroll
  for (int i=0;i<3;i++){
    #pragma unroll
    for (int r=0;r<4;r++){
      int row = i*16 + quad*4 + r;
      float m = mrow[row];
      float ls = 0.f;
      #pragma unroll
      for (int j=0;j<4;j++){
        float e = __expf(S[i][j][r] - m);
        ls += e;
        Ps[row*PSTR + w*64 + j*16 + qlane] = f2b(e);
      }
      ls += __shfl_xor(ls, 1);
      ls += __shfl_xor(ls, 2);
      ls += __shfl_xor(ls, 4);
      ls += __shfl_xor(ls, 8);
      if (qlane == 0) wred[w][row] = ls;
    }
  }
  __syncthreads();
  if (t < 48){
    pM[(bh*NCH + c)*48 + t] = mrow[t];
    pS[(bh*NCH + c)*48 + t] = wred[0][t] + wred[1][t] + wred[2][t] + wred[3][t];
  }
  f32x4 O[3];
  #pragma unroll
  for (int i=0;i<3;i++) O[i] = (f32x4){0.f,0.f,0.f,0.f};
  for (int half = 0; half < 2; ++half){
    __syncthreads();
    for (int idx = t; idx < 128*64; idx += 256){
      int rr = idx >> 6, d = idx & 63;
      VsT[d*VSTR + rr] = vbase[(size_t)(l0 + half*128 + rr)*DD + d];
    }
    __syncthreads();
    #pragma unroll
    for (int ks = 0; ks < 4; ++ks){
      int kloc = half*128 + ks*32;
      bf16x8 bfv = *(const bf16x8*)(VsT + (w*16 + qlane)*VSTR + ks*32 + quad*8);
      #pragma unroll
      for (int i=0;i<3;i++){
        bf16x8 af = *(const bf16x8*)(Ps + (i*16 + qlane)*PSTR + kloc + quad*8);
        O[i] = __builtin_amdgcn_mfma_f32_16x16x32_bf16(af, bfv, O[i], 0, 0, 0);
      }
    }
  }
  size_t ob = (size_t)(bh*NCH + c)*48*64;
  #pragma unroll
  for (int i=0;i<3;i++)
    #pragma unroll
    for (int r=0;r<4;r++)
      pO[ob + (size_t)(i*16 + quad*4 + r)*64 + w*16 + qlane] = O[i][r];
}

// ---------------- flash combine: merge chunk partials, scatter into ctxB ----------------
__global__ __launch_bounds__(256) void k_flash_red(const float* __restrict__ pO, const float* __restrict__ pM,
    const float* __restrict__ pS, const int* __restrict__ sidx, u16* __restrict__ ctxB){
  int bh = blockIdx.x; int b = bh >> 3, hh = bh & 7;
  int t = threadIdx.x;
  for (int idx = t; idx < UU*64; idx += 256){
    int u = idx >> 6, n = idx & 63;
    float m = -3.0e38f;
    #pragma unroll
    for (int c=0;c<NCH;c++) m = fmaxf(m, pM[(bh*NCH + c)*48 + u]);
    float s = 0.f, o = 0.f;
    #pragma unroll
    for (int c=0;c<NCH;c++){
      float wgt = __expf(pM[(bh*NCH + c)*48 + u] - m);
      s += wgt * pS[(bh*NCH + c)*48 + u];
      o += wgt * pO[((size_t)(bh*NCH + c)*48 + u)*64 + n];
    }
    int qrow = sidx[bh*UU + u];
    ctxB[(size_t)(b*LL + qrow)*DD + hh*DHH + n] = f2b(o / s);
  }
}

// ---------------- add+LN: one wave per row, shuffle reductions, no barriers ----------------
__global__ __launch_bounds__(256) void k_addln(const float* __restrict__ a, const float* __restrict__ r,
    const float* __restrict__ g, const float* __restrict__ bvec, float* __restrict__ out,
    u16* __restrict__ outB){
  int row = blockIdx.x*4 + (threadIdx.x >> 6);
  int lane = threadIdx.x & 63;
  size_t base = (size_t)row * DD + lane*8;
  float4 a0 = *(const float4*)(a + base);
  float4 a1 = *(const float4*)(a + base + 4);
  float4 r0 = *(const float4*)(r + base);
  float4 r1 = *(const float4*)(r + base + 4);
  float x[8] = {a0.x+r0.x, a0.y+r0.y, a0.z+r0.z, a0.w+r0.w,
                a1.x+r1.x, a1.y+r1.y, a1.z+r1.z, a1.w+r1.w};
  float s = 0.f;
  #pragma unroll
  for (int i=0;i<8;i++) s += x[i];
  #pragma unroll
  for (int off=1; off<64; off<<=1) s += __shfl_xor(s, off);
  float mean = s * (1.0f/DD);
  float vs = 0.f;
  #pragma unroll
  for (int i=0;i<8;i++){ x[i] -= mean; vs += x[i]*x[i]; }
  #pragma unroll
  for (int off=1; off<64; off<<=1) vs += __shfl_xor(vs, off);
  float rs = rsqrtf(vs * (1.0f/DD) + 1e-5f);
  const float* gp = g + lane*8;
  const float* bp = bvec + lane*8;
  float o[8];
  u16 ob[8];
  #pragma unroll
  for (int i=0;i<8;i++){ o[i] = x[i]*rs*gp[i] + bp[i]; ob[i] = f2b(o[i]); }
  *(float4*)(out + base)     = (float4){o[0],o[1],o[2],o[3]};
  *(float4*)(out + base + 4) = (float4){o[4],o[5],o[6],o[7]};
  *(ushort4*)(outB + base)     = (ushort4){ob[0],ob[1],ob[2],ob[3]};
  *(ushort4*)(outB + base + 4) = (ushort4){ob[4],ob[5],ob[6],ob[7]};
}

// ---------------- final projection ----------------
__global__ __launch_bounds__(64) void k_proj(const float* __restrict__ h, const float* __restrict__ pw,
    const float* __restrict__ pb, void* __restrict__ out, const int* __restrict__ flag){
  int rp = blockIdx.x; int b = rp / PP, pp = rp % PP;
  int t = threadIdx.x;
  const float* hr = h + (size_t)(b*LL + (LL-PP) + pp) * DD;
  float acc[EE];
  #pragma unroll
  for (int e=0;e<EE;e++) acc[e]=0.f;
  for (int d = t; d < DD; d += 64){
    float hv = hr[d];
    #pragma unroll
    for (int e=0;e<EE;e++) acc[e] = fmaf(hv, pw[d*EE+e], acc[e]);
  }
  int isbf = *flag;
  #pragma unroll
  for (int e=0;e<EE;e++){
    float rr = acc[e];
    for (int off=32; off>0; off>>=1) rr += __shfl_down(rr, off);
    if (t == 0){
      float val = rr + pb[e];
      if (isbf) ((__hip_bfloat16*)out)[(size_t)rp*EE + e] = __float2bfloat16(val);
      else      ((float*)out)[(size_t)rp*EE + e] = val;
    }
  }
}

extern "C" void kernel_launch(void* const* d_in, const int* in_sizes, int n_in,
                              void* d_out, int out_size, void* d_ws, size_t ws_size,
                              hipStream_t stream){
  float* ws    = (float*)d_ws;
  float* h     = ws;                                  // BIGN
  float* Mv    = ws + BIGN;                           // 65536
  float* ksum  = Mv + (size_t)BB*HH*LL;               // 2048
  float* vsum  = ksum + 2048;                         // 2048 (contiguous after ksum!)
  float* pM    = vsum + 2048;                         // 12288
  float* pS    = pM + 12288;                          // 12288
  float* pO    = pS + 12288;                          // 786432
  float* tmpF  = pO + 786432;                         // BIGN
  int*   sidx  = (int*)(tmpF + BIGN);                 // 1280
  int*   flag  = sidx + 1280;
  u16*   hB    = (u16*)(flag + 4);
  u16*   qB    = hB + BIGN;
  u16*   kB    = qB + BIGN;
  u16*   vB    = kB + BIGN;
  u16*   ctxB  = vB + BIGN;
  u16*   f1B   = ctxB + BIGN;
  u16*   wT    = f1B + BIGN;                          // 12*512*512 u16
  float* conv  = (float*)(wT + (size_t)12*DD*DD);

  static const int small_ids[NSMALL] = {0,1,2,4,6,8,10,12,14,15,16,17,18,19,20};
  ConvArgs ca;
  int off_all[NIN];
  int tot = 0, maxn = 0;
  for (int i = 0; i < NIN; ++i) off_all[i] = -1;
  for (int s = 0; s < NSMALL; ++s){
    int i = small_ids[s];
    ca.src[s] = d_in[i];
    ca.off[s] = tot;
    ca.n[s]   = in_sizes[i];
    off_all[i] = tot;
    tot += in_sizes[i];
    if (in_sizes[i] > maxn) maxn = in_sizes[i];
  }
  const float* x     = conv + off_all[0];
  const float* emb_w = conv + off_all[1];
  const float* emb_b = conv + off_all[2];
  const float* bq = conv + off_all[4];
  const float* bk = conv + off_all[6];
  const float* bv = conv + off_all[8];
  const float* bo = conv + off_all[10];
  const float* b1 = conv + off_all[12];
  const float* b2 = conv + off_all[14];
  const float* ln1g = conv + off_all[15]; const float* ln1b = conv + off_all[16];
  const float* ln2g = conv + off_all[17]; const float* ln2b = conv + off_all[18];
  const float* pw = conv + off_all[19]; const float* pb = conv + off_all[20];

  WPtrs wp;
  wp.p[0]=d_in[3]; wp.p[1]=d_in[5]; wp.p[2]=d_in[7];
  wp.p[3]=d_in[9]; wp.p[4]=d_in[11]; wp.p[5]=d_in[13];

  k_probe<<<1, 64, 0, stream>>>(d_in[15], flag);
  k_convert<<<dim3((maxn + 255)/256, NSMALL), 256, 0, stream>>>(ca, conv, flag);
  k_wt<<<dim3(8, 8, 12), 256, 0, stream>>>(wp, wT, flag);

  dim3 gg(DD/128, ROWS/128);     // (4,64)
  dim3 gq(3*DD/128, ROWS/128);   // (12,64) fused QKV

  k_embed<<<ROWS*DD/256, 256, 0, stream>>>(x, emb_w, emb_b, h, hB);
  for (int l = 0; l < NLAYER; ++l){
    const u16* WqkvT = wT + (size_t)(l*6 + 0)*DD*DD;
    const u16* WoT   = wT + (size_t)(l*6 + 3)*DD*DD;
    const u16* W1T   = wT + (size_t)(l*6 + 4)*DD*DD;
    const u16* W2T   = wT + (size_t)(l*6 + 5)*DD*DD;

    k_zero<<<16, 256, 0, stream>>>(ksum);
    k_gemm_qkv<<<gq, 256, 0, stream>>>(hB, WqkvT, bq + l*DD, bk + l*DD, bv + l*DD,
                                       qB, kB, vB, ksum, vsum);
    k_sparsity_mfma<<<dim3(LL/64, BB*HH), 256, 0, stream>>>(qB, kB, ksum, Mv);
    k_topk<<<BB*HH, 64, 0, stream>>>(Mv, sidx);
    k_fill_ctx<<<ROWS*DD/256, 256, 0, stream>>>(vsum, ctxB);
    k_flash<<<dim3(NCH, BB*HH), 256, 0, stream>>>(qB, kB, vB, sidx, pO, pM, pS);
    k_flash_red<<<BB*HH, 256, 0, stream>>>(pO, pM, pS, sidx, ctxB);
    k_gemm_mfma<<<gg, 256, 0, stream>>>(ctxB, WoT, bo + l*DD, tmpF, nullptr, 0);
    k_addln<<<ROWS/4, 256, 0, stream>>>(h, tmpF, ln1g + l*DD, ln1b + l*DD, h, hB);
    k_gemm_mfma<<<gg, 256, 0, stream>>>(hB, W1T, b1 + l*DD, nullptr, f1B, 1);
    k_gemm_mfma<<<gg, 256, 0, stream>>>(f1B, W2T, b2 + l*DD, tmpF, nullptr, 0);
    k_addln<<<ROWS/4, 256, 0, stream>>>(h, tmpF, ln2g + l*DD, ln2b + l*DD, h, hB);
  }
  k_proj<<<BB*PP, 64, 0, stream>>>(h, pw, pb, d_out, flag);
}